// Round 1
// baseline (621.561 us; speedup 1.0000x reference)
//
#include <hip/hip_runtime.h>
#include <math.h>

// ---------------------------------------------------------------------------
// GAT_E_to_R: N=100000 nodes, E=500000 edges, EH=256, RH=128, R=1000
// out[R,128] = sum over edges of alpha_h*msg_h[h] + alpha_t*msg_t[t], grouped
// by rel, with segment-softmax'd leaky-relu attention logits.
// ---------------------------------------------------------------------------

#define EHD 256
#define RHD 128

__device__ __forceinline__ float leaky(float x) { return x > 0.f ? x : 0.01f * x; }

// ---------------- Kernel 1: x_r_h = x_e @ w_h ; x_r_t = x_e @ w_t -----------
// A [N,256] row-major shared between both B's. BM=64, BN=128(full), BK=32.
// 256 threads: tx=tid&15 owns cols {tx*4..+3, 64+tx*4..+3}; ty=tid>>4 owns rows ty*4..+3.
__global__ __launch_bounds__(256) void k_xr(
    const float* __restrict__ xe, const float* __restrict__ wh,
    const float* __restrict__ wt, float* __restrict__ xrh,
    float* __restrict__ xrt, int N)
{
    __shared__ float As[32][68];     // transposed: As[k][row]
    __shared__ float Bh[32][128];
    __shared__ float Bt[32][128];
    const int tid = threadIdx.x;
    const int tx = tid & 15, ty = tid >> 4;
    const int m0 = blockIdx.x * 64;

    float acch[4][8], acct[4][8];
#pragma unroll
    for (int r = 0; r < 4; r++)
#pragma unroll
        for (int c = 0; c < 8; c++) { acch[r][c] = 0.f; acct[r][c] = 0.f; }

    for (int kt = 0; kt < EHD; kt += 32) {
#pragma unroll
        for (int i = 0; i < 2; i++) {            // A tile 64x32 = 512 float4
            int q = tid + i * 256;
            int row = q >> 3;
            int kc = (q & 7) << 2;
            float4 v = make_float4(0.f, 0.f, 0.f, 0.f);
            int gr = m0 + row;
            if (gr < N) v = *reinterpret_cast<const float4*>(xe + (size_t)gr * EHD + kt + kc);
            As[kc + 0][row] = v.x; As[kc + 1][row] = v.y;
            As[kc + 2][row] = v.z; As[kc + 3][row] = v.w;
        }
#pragma unroll
        for (int i = 0; i < 4; i++) {            // B tiles 32x128 each
            int q = tid + i * 256;
            int row = q >> 5;
            int c4 = (q & 31) << 2;
            *reinterpret_cast<float4*>(&Bh[row][c4]) =
                *reinterpret_cast<const float4*>(wh + (size_t)(kt + row) * RHD + c4);
            *reinterpret_cast<float4*>(&Bt[row][c4]) =
                *reinterpret_cast<const float4*>(wt + (size_t)(kt + row) * RHD + c4);
        }
        __syncthreads();
#pragma unroll 4
        for (int k = 0; k < 32; k++) {
            const float4 a4  = *reinterpret_cast<const float4*>(&As[k][ty * 4]);
            const float4 bh0 = *reinterpret_cast<const float4*>(&Bh[k][tx * 4]);
            const float4 bh1 = *reinterpret_cast<const float4*>(&Bh[k][64 + tx * 4]);
            const float4 bt0 = *reinterpret_cast<const float4*>(&Bt[k][tx * 4]);
            const float4 bt1 = *reinterpret_cast<const float4*>(&Bt[k][64 + tx * 4]);
            const float av[4]  = {a4.x, a4.y, a4.z, a4.w};
            const float bhv[8] = {bh0.x, bh0.y, bh0.z, bh0.w, bh1.x, bh1.y, bh1.z, bh1.w};
            const float btv[8] = {bt0.x, bt0.y, bt0.z, bt0.w, bt1.x, bt1.y, bt1.z, bt1.w};
#pragma unroll
            for (int r = 0; r < 4; r++)
#pragma unroll
                for (int c = 0; c < 8; c++) {
                    acch[r][c] = fmaf(av[r], bhv[c], acch[r][c]);
                    acct[r][c] = fmaf(av[r], btv[c], acct[r][c]);
                }
        }
        __syncthreads();
    }
#pragma unroll
    for (int r = 0; r < 4; r++) {
        int row = m0 + ty * 4 + r;
        if (row >= N) continue;
        float4 o;
        o = make_float4(acch[r][0], acch[r][1], acch[r][2], acch[r][3]);
        *reinterpret_cast<float4*>(xrh + (size_t)row * RHD + tx * 4) = o;
        o = make_float4(acch[r][4], acch[r][5], acch[r][6], acch[r][7]);
        *reinterpret_cast<float4*>(xrh + (size_t)row * RHD + 64 + tx * 4) = o;
        o = make_float4(acct[r][0], acct[r][1], acct[r][2], acct[r][3]);
        *reinterpret_cast<float4*>(xrt + (size_t)row * RHD + tx * 4) = o;
        o = make_float4(acct[r][4], acct[r][5], acct[r][6], acct[r][7]);
        *reinterpret_cast<float4*>(xrt + (size_t)row * RHD + 64 + tx * 4) = o;
    }
}

// ---------------- Kernel 2: msg = x_r @ r_w + b + x_r (in place) ------------
// Also emits per-node scalars s1=xrh.a_h1, s2=xrt.a_h2, s3=xrh.a_t1, s4=xrt.a_t2
__global__ __launch_bounds__(256) void k_msg(
    float* __restrict__ xrh, float* __restrict__ xrt,
    const float* __restrict__ rhw, const float* __restrict__ rtw,
    const float* __restrict__ rhb, const float* __restrict__ rtb,
    const float* __restrict__ ah1, const float* __restrict__ ah2,
    const float* __restrict__ at1, const float* __restrict__ at2,
    float* __restrict__ s1, float* __restrict__ s2,
    float* __restrict__ s3, float* __restrict__ s4, int N)
{
    __shared__ float Ah[32][68], At[32][68];
    __shared__ float Bh[32][128], Bt[32][128];
    const int tid = threadIdx.x;
    const int tx = tid & 15, ty = tid >> 4;
    const int m0 = blockIdx.x * 64;

    float acch[4][8], acct[4][8];
#pragma unroll
    for (int r = 0; r < 4; r++)
#pragma unroll
        for (int c = 0; c < 8; c++) { acch[r][c] = 0.f; acct[r][c] = 0.f; }

    for (int kt = 0; kt < RHD; kt += 32) {
#pragma unroll
        for (int i = 0; i < 2; i++) {
            int q = tid + i * 256;
            int row = q >> 3;
            int kc = (q & 7) << 2;
            int gr = m0 + row;
            float4 vh = make_float4(0.f, 0.f, 0.f, 0.f), vt = vh;
            if (gr < N) {
                vh = *reinterpret_cast<const float4*>(xrh + (size_t)gr * RHD + kt + kc);
                vt = *reinterpret_cast<const float4*>(xrt + (size_t)gr * RHD + kt + kc);
            }
            Ah[kc + 0][row] = vh.x; Ah[kc + 1][row] = vh.y;
            Ah[kc + 2][row] = vh.z; Ah[kc + 3][row] = vh.w;
            At[kc + 0][row] = vt.x; At[kc + 1][row] = vt.y;
            At[kc + 2][row] = vt.z; At[kc + 3][row] = vt.w;
        }
#pragma unroll
        for (int i = 0; i < 4; i++) {
            int q = tid + i * 256;
            int row = q >> 5;
            int c4 = (q & 31) << 2;
            *reinterpret_cast<float4*>(&Bh[row][c4]) =
                *reinterpret_cast<const float4*>(rhw + (size_t)(kt + row) * RHD + c4);
            *reinterpret_cast<float4*>(&Bt[row][c4]) =
                *reinterpret_cast<const float4*>(rtw + (size_t)(kt + row) * RHD + c4);
        }
        __syncthreads();
#pragma unroll 4
        for (int k = 0; k < 32; k++) {
            const float4 a4h = *reinterpret_cast<const float4*>(&Ah[k][ty * 4]);
            const float4 a4t = *reinterpret_cast<const float4*>(&At[k][ty * 4]);
            const float4 bh0 = *reinterpret_cast<const float4*>(&Bh[k][tx * 4]);
            const float4 bh1 = *reinterpret_cast<const float4*>(&Bh[k][64 + tx * 4]);
            const float4 bt0 = *reinterpret_cast<const float4*>(&Bt[k][tx * 4]);
            const float4 bt1 = *reinterpret_cast<const float4*>(&Bt[k][64 + tx * 4]);
            const float avh[4] = {a4h.x, a4h.y, a4h.z, a4h.w};
            const float avt[4] = {a4t.x, a4t.y, a4t.z, a4t.w};
            const float bhv[8] = {bh0.x, bh0.y, bh0.z, bh0.w, bh1.x, bh1.y, bh1.z, bh1.w};
            const float btv[8] = {bt0.x, bt0.y, bt0.z, bt0.w, bt1.x, bt1.y, bt1.z, bt1.w};
#pragma unroll
            for (int r = 0; r < 4; r++)
#pragma unroll
                for (int c = 0; c < 8; c++) {
                    acch[r][c] = fmaf(avh[r], bhv[c], acch[r][c]);
                    acct[r][c] = fmaf(avt[r], btv[c], acct[r][c]);
                }
        }
        __syncthreads();
    }

    // epilogue: bias + residual, s-scalars, in-place store
    float A1[8], A2[8], A3[8], A4[8], BHv[8], BTv[8];
#pragma unroll
    for (int c = 0; c < 8; c++) {
        int col = (c < 4) ? (tx * 4 + c) : (64 + tx * 4 + (c - 4));
        A1[c] = ah1[col]; A2[c] = ah2[col]; A3[c] = at1[col]; A4[c] = at2[col];
        BHv[c] = rhb[col]; BTv[c] = rtb[col];
    }
    float s1p[4] = {0, 0, 0, 0}, s2p[4] = {0, 0, 0, 0};
    float s3p[4] = {0, 0, 0, 0}, s4p[4] = {0, 0, 0, 0};
#pragma unroll
    for (int r = 0; r < 4; r++) {
        int row = m0 + ty * 4 + r;
        bool ok = row < N;
        float4 xh0 = make_float4(0,0,0,0), xh1 = xh0, xt0 = xh0, xt1 = xh0;
        if (ok) {
            xh0 = *reinterpret_cast<const float4*>(xrh + (size_t)row * RHD + tx * 4);
            xh1 = *reinterpret_cast<const float4*>(xrh + (size_t)row * RHD + 64 + tx * 4);
            xt0 = *reinterpret_cast<const float4*>(xrt + (size_t)row * RHD + tx * 4);
            xt1 = *reinterpret_cast<const float4*>(xrt + (size_t)row * RHD + 64 + tx * 4);
        }
        const float xh[8] = {xh0.x, xh0.y, xh0.z, xh0.w, xh1.x, xh1.y, xh1.z, xh1.w};
        const float xt[8] = {xt0.x, xt0.y, xt0.z, xt0.w, xt1.x, xt1.y, xt1.z, xt1.w};
#pragma unroll
        for (int c = 0; c < 8; c++) {
            s1p[r] = fmaf(xh[c], A1[c], s1p[r]);
            s3p[r] = fmaf(xh[c], A3[c], s3p[r]);
            s2p[r] = fmaf(xt[c], A2[c], s2p[r]);
            s4p[r] = fmaf(xt[c], A4[c], s4p[r]);
            acch[r][c] += BHv[c] + xh[c];
            acct[r][c] += BTv[c] + xt[c];
        }
        if (ok) {
            float4 o;
            o = make_float4(acch[r][0], acch[r][1], acch[r][2], acch[r][3]);
            *reinterpret_cast<float4*>(xrh + (size_t)row * RHD + tx * 4) = o;
            o = make_float4(acch[r][4], acch[r][5], acch[r][6], acch[r][7]);
            *reinterpret_cast<float4*>(xrh + (size_t)row * RHD + 64 + tx * 4) = o;
            o = make_float4(acct[r][0], acct[r][1], acct[r][2], acct[r][3]);
            *reinterpret_cast<float4*>(xrt + (size_t)row * RHD + tx * 4) = o;
            o = make_float4(acct[r][4], acct[r][5], acct[r][6], acct[r][7]);
            *reinterpret_cast<float4*>(xrt + (size_t)row * RHD + 64 + tx * 4) = o;
        }
    }
    // reduce s partials across the 16 tx lanes (contiguous lanes within a wave)
#pragma unroll
    for (int off = 1; off < 16; off <<= 1) {
#pragma unroll
        for (int r = 0; r < 4; r++) {
            s1p[r] += __shfl_xor(s1p[r], off);
            s2p[r] += __shfl_xor(s2p[r], off);
            s3p[r] += __shfl_xor(s3p[r], off);
            s4p[r] += __shfl_xor(s4p[r], off);
        }
    }
    if (tx == 0) {
#pragma unroll
        for (int r = 0; r < 4; r++) {
            int row = m0 + ty * 4 + r;
            if (row < N) {
                s1[row] = s1p[r]; s2[row] = s2p[r];
                s3[row] = s3p[r]; s4[row] = s4p[r];
            }
        }
    }
}

// ---------------- CSR sort by relation --------------------------------------
__global__ void k_hist(const int* __restrict__ rel, int* __restrict__ counts, int E)
{
    int e = blockIdx.x * blockDim.x + threadIdx.x;
    if (e < E) atomicAdd(&counts[rel[e]], 1);
}

__global__ __launch_bounds__(1024) void k_scan(
    const int* __restrict__ counts, int* __restrict__ starts,
    int* __restrict__ cursor, int R, int E)
{
    __shared__ int buf[2][1024];
    int t = threadIdx.x;
    int v = (t < R) ? counts[t] : 0;
    buf[0][t] = v;
    int cur = 0;
    for (int off = 1; off < 1024; off <<= 1) {
        __syncthreads();
        int x = buf[cur][t];
        if (t >= off) x += buf[cur][t - off];
        buf[cur ^ 1][t] = x;
        cur ^= 1;
    }
    __syncthreads();
    int incl = buf[cur][t];
    if (t < R) { starts[t] = incl - v; cursor[t] = incl - v; }
    if (t == 0) starts[R] = E;
}

__global__ void k_scatter(const int* __restrict__ rel, int* __restrict__ cursor,
                          int* __restrict__ sorted, int E)
{
    int e = blockIdx.x * blockDim.x + threadIdx.x;
    if (e < E) {
        int pos = atomicAdd(&cursor[rel[e]], 1);
        sorted[pos] = e;
    }
}

// ---------------- Kernel 6: per-relation softmax + weighted reduce ----------
__global__ __launch_bounds__(256) void k_rel(
    const int* __restrict__ sorted, const int* __restrict__ starts,
    const int* __restrict__ eh, const int* __restrict__ et,
    const float* __restrict__ s1, const float* __restrict__ s2,
    const float* __restrict__ s3, const float* __restrict__ s4,
    const float* __restrict__ msgh, const float* __restrict__ msgt,
    float* __restrict__ out)
{
    const int r = blockIdx.x;
    const int start = starts[r], end = starts[r + 1];
    const int tid = threadIdx.x;
    if (start >= end) {
        if (tid < 128) out[(size_t)r * RHD + tid] = 0.f;
        return;
    }
    __shared__ float red[8];

    // pass 1: segment max of leaky-relu logits
    float m1 = -INFINITY, m2 = -INFINITY;
    for (int i = start + tid; i < end; i += 256) {
        int e = sorted[i];
        int h = eh[e], t = et[e];
        float e1 = leaky(s1[h] + s2[t]);
        float e2 = leaky(s3[h] + s4[t]);
        m1 = fmaxf(m1, e1); m2 = fmaxf(m2, e2);
    }
#pragma unroll
    for (int off = 32; off > 0; off >>= 1) {
        m1 = fmaxf(m1, __shfl_xor(m1, off));
        m2 = fmaxf(m2, __shfl_xor(m2, off));
    }
    const int w = tid >> 6;
    if ((tid & 63) == 0) { red[w * 2] = m1; red[w * 2 + 1] = m2; }
    __syncthreads();
    m1 = fmaxf(fmaxf(red[0], red[2]), fmaxf(red[4], red[6]));
    m2 = fmaxf(fmaxf(red[1], red[3]), fmaxf(red[5], red[7]));
    __syncthreads();

    // pass 2: segment sum of exp
    float sum1 = 0.f, sum2 = 0.f;
    for (int i = start + tid; i < end; i += 256) {
        int e = sorted[i];
        int h = eh[e], t = et[e];
        float e1 = leaky(s1[h] + s2[t]);
        float e2 = leaky(s3[h] + s4[t]);
        sum1 += __expf(e1 - m1);
        sum2 += __expf(e2 - m2);
    }
#pragma unroll
    for (int off = 32; off > 0; off >>= 1) {
        sum1 += __shfl_xor(sum1, off);
        sum2 += __shfl_xor(sum2, off);
    }
    if ((tid & 63) == 0) { red[w * 2] = sum1; red[w * 2 + 1] = sum2; }
    __syncthreads();
    sum1 = red[0] + red[2] + red[4] + red[6];
    sum2 = red[1] + red[3] + red[5] + red[7];
    const float inv1 = 1.f / sum1, inv2 = 1.f / sum2;

    // pass 3: weighted accumulate. threads 0..127 own cols (h side),
    // threads 128..255 own cols (t side).
    __shared__ float alph[2][256];
    __shared__ int   nds[2][256];
    const int j = tid & 127;
    const int side = tid >> 7;
    const float* __restrict__ mbase = side ? msgt : msgh;
    float a0 = 0.f, a1 = 0.f, a2 = 0.f, a3 = 0.f;

    for (int c0 = start; c0 < end; c0 += 256) {
        __syncthreads();
        int i = c0 + tid;
        if (i < end) {
            int e = sorted[i];
            int h = eh[e], t = et[e];
            float e1 = leaky(s1[h] + s2[t]);
            float e2 = leaky(s3[h] + s4[t]);
            alph[0][tid] = __expf(e1 - m1) * inv1;
            alph[1][tid] = __expf(e2 - m2) * inv2;
            nds[0][tid] = h; nds[1][tid] = t;
        }
        __syncthreads();
        const int nc = min(256, end - c0);
        int q = 0;
        for (; q + 4 <= nc; q += 4) {
            float w0 = alph[side][q + 0]; int n0 = nds[side][q + 0];
            float w1 = alph[side][q + 1]; int n1 = nds[side][q + 1];
            float w2 = alph[side][q + 2]; int n2 = nds[side][q + 2];
            float w3 = alph[side][q + 3]; int n3 = nds[side][q + 3];
            a0 = fmaf(w0, mbase[(size_t)n0 * RHD + j], a0);
            a1 = fmaf(w1, mbase[(size_t)n1 * RHD + j], a1);
            a2 = fmaf(w2, mbase[(size_t)n2 * RHD + j], a2);
            a3 = fmaf(w3, mbase[(size_t)n3 * RHD + j], a3);
        }
        for (; q < nc; q++)
            a0 = fmaf(alph[side][q], mbase[(size_t)nds[side][q] * RHD + j], a0);
    }
    float acc = a0 + a1 + a2 + a3;

    __shared__ float comb[128];
    __syncthreads();
    if (side) comb[j] = acc;
    __syncthreads();
    if (!side) out[(size_t)r * RHD + j] = acc + comb[j];
}

// ---------------------------------------------------------------------------
extern "C" void kernel_launch(void* const* d_in, const int* in_sizes, int n_in,
                              void* d_out, int out_size, void* d_ws, size_t ws_size,
                              hipStream_t stream)
{
    const float* xe  = (const float*)d_in[0];
    const int*  eidx = (const int*)d_in[1];
    const int*  rel  = (const int*)d_in[2];
    // d_in[3] = rel_all (unused by reference)
    const float* wh  = (const float*)d_in[4];
    const float* wt  = (const float*)d_in[5];
    const float* ah1 = (const float*)d_in[6];
    const float* ah2 = (const float*)d_in[7];
    const float* at1 = (const float*)d_in[8];
    const float* at2 = (const float*)d_in[9];
    const float* rhw = (const float*)d_in[10];
    const float* rhb = (const float*)d_in[11];
    const float* rtw = (const float*)d_in[12];
    const float* rtb = (const float*)d_in[13];
    float* out = (float*)d_out;

    const int N = in_sizes[0] / EHD;
    const int E = in_sizes[2];
    const int R = out_size / RHD;
    const int* eh = eidx;
    const int* et = eidx + E;

    char* ws = (char*)d_ws;
    size_t off = 0;
    auto alloc = [&](size_t bytes) -> void* {
        void* p = ws + off;
        off = (off + bytes + 255) & ~(size_t)255;
        return p;
    };
    float* xrh   = (float*)alloc((size_t)N * RHD * sizeof(float)); // becomes msg_h
    float* xrt   = (float*)alloc((size_t)N * RHD * sizeof(float)); // becomes msg_t
    float* s1    = (float*)alloc((size_t)N * sizeof(float));
    float* s2    = (float*)alloc((size_t)N * sizeof(float));
    float* s3    = (float*)alloc((size_t)N * sizeof(float));
    float* s4    = (float*)alloc((size_t)N * sizeof(float));
    int* counts  = (int*)alloc((size_t)R * sizeof(int));
    int* starts  = (int*)alloc((size_t)(R + 1) * sizeof(int));
    int* cursor  = (int*)alloc((size_t)R * sizeof(int));
    int* sorted  = (int*)alloc((size_t)E * sizeof(int));
    (void)ws_size; (void)n_in;

    hipMemsetAsync(counts, 0, (size_t)R * sizeof(int), stream);

    k_xr<<<(N + 63) / 64, 256, 0, stream>>>(xe, wh, wt, xrh, xrt, N);
    k_msg<<<(N + 63) / 64, 256, 0, stream>>>(xrh, xrt, rhw, rtw, rhb, rtb,
                                             ah1, ah2, at1, at2,
                                             s1, s2, s3, s4, N);
    k_hist<<<(E + 255) / 256, 256, 0, stream>>>(rel, counts, E);
    k_scan<<<1, 1024, 0, stream>>>(counts, starts, cursor, R, E);
    k_scatter<<<(E + 255) / 256, 256, 0, stream>>>(rel, cursor, sorted, E);
    k_rel<<<R, 256, 0, stream>>>(sorted, starts, eh, et, s1, s2, s3, s4,
                                 xrh, xrt, out);
}

// Round 2
// 433.852 us; speedup vs baseline: 1.4327x; 1.4327x over previous
//
#include <hip/hip_runtime.h>
#include <hip/hip_bf16.h>
#include <math.h>

// ---------------------------------------------------------------------------
// GAT_E_to_R: N=100000, E=500000, EH=256, RH=128, R=1000
// Dense pipeline (2 GEMMs + scalars + bias/residual) fused into one bf16-MFMA
// kernel; edge softmax/reduction via CSR sort + per-relation blocks.
// ---------------------------------------------------------------------------

#define EHD 256
#define RHD 128
#define BSTR 40    // Bs row stride in shorts: 32 + 8 pad -> 80B (16B-aligned, 2-way)
#define XSTR 136   // Xs row stride in shorts: 128 + 8 pad -> 272B (16B-aligned, 2-way)

typedef __attribute__((ext_vector_type(8))) short short8;
typedef __attribute__((ext_vector_type(4))) float f32x4;

__device__ __forceinline__ short f2bf(float x) {
    __hip_bfloat16 b = __float2bfloat16(x);   // RNE
    return *reinterpret_cast<short*>(&b);
}
__device__ __forceinline__ float bf2f(short s) {
    __hip_bfloat16 b = *reinterpret_cast<__hip_bfloat16*>(&s);
    return __bfloat162float(b);
}
__device__ __forceinline__ float leaky(float x) { return x > 0.f ? x : 0.01f * x; }

// ---- transpose+convert: dst[n][k] (bf16) = src[k][n] (fp32) ----------------
__global__ __launch_bounds__(256) void k_prep(const float* __restrict__ src,
                                              short* __restrict__ dst,
                                              int K, int Nc)
{
    __shared__ float t[32][33];
    const int k0 = blockIdx.x * 32, n0 = blockIdx.y * 32;
    const int tr = threadIdx.x >> 3, tc = (threadIdx.x & 7) << 2;
    float4 v = *reinterpret_cast<const float4*>(src + (size_t)(k0 + tr) * Nc + n0 + tc);
    t[tr][tc + 0] = v.x; t[tr][tc + 1] = v.y;
    t[tr][tc + 2] = v.z; t[tr][tc + 3] = v.w;
    __syncthreads();
    short* o = dst + (size_t)(n0 + tr) * K + k0 + tc;
    o[0] = f2bf(t[tc + 0][tr]); o[1] = f2bf(t[tc + 1][tr]);
    o[2] = f2bf(t[tc + 2][tr]); o[3] = f2bf(t[tc + 3][tr]);
}

// ---- fused: xr = xe@{wh,wt}; s1..s4; msg = xr@{rhw,rtw} + b + xr ------------
// 256 threads = 4 waves; block owns 64 rows. Wave w owns rows w*16..w*16+15.
// MFMA 16x16x32 bf16: A row=lane&15, k=(lane>>4)*8+e ; B col=lane&15, same k ;
// D col=lane&15, row=(lane>>4)*4+reg  [HW-verified mapping].
__global__ __launch_bounds__(256, 2) void k_fused(
    const float* __restrict__ xe,
    const short* __restrict__ whT, const short* __restrict__ wtT,   // [128][256]
    const short* __restrict__ rhwT, const short* __restrict__ rtwT, // [128][128]
    const float* __restrict__ rhb, const float* __restrict__ rtb,
    const float* __restrict__ ah1, const float* __restrict__ ah2,
    const float* __restrict__ at1, const float* __restrict__ at2,
    float* __restrict__ s1, float* __restrict__ s2,
    float* __restrict__ s3, float* __restrict__ s4,
    float* __restrict__ msgh, float* __restrict__ msgt, int N)
{
    __shared__ __align__(16) short Bs[2][128][BSTR];   // 20480 B
    __shared__ __align__(16) short Xs[2][64][XSTR];    // 34816 B

    const int tid = threadIdx.x;
    const int w = tid >> 6, l = tid & 63;
    const int ln = l & 15, lk = l >> 4;
    const int m0 = blockIdx.x * 64;
    const int sn = tid >> 1, sh = (tid & 1) << 4;      // B-staging mapping
    const int orow = (w << 4) + (lk << 2);             // D local row base

    f32x4 acch[8], acct[8];
#pragma unroll
    for (int c = 0; c < 8; c++) {
        acch[c] = (f32x4){0.f, 0.f, 0.f, 0.f};
        acct[c] = (f32x4){0.f, 0.f, 0.f, 0.f};
    }

    // -------- GEMM1: K=256, 8 k-steps --------
    const int arow = m0 + (w << 4) + ln;
    const int aclamp = min(arow, N - 1);
    const float* abase = xe + (size_t)aclamp * EHD + (lk << 3);

    for (int kt = 0; kt < EHD; kt += 32) {
        __syncthreads();
        {   // stage B (bf16, already [n][k]): 16 shorts/thread/matrix
            const short* p0 = whT + (size_t)sn * EHD + kt + sh;
            const short* p1 = wtT + (size_t)sn * EHD + kt + sh;
            *reinterpret_cast<short8*>(&Bs[0][sn][sh + 0]) = *reinterpret_cast<const short8*>(p0);
            *reinterpret_cast<short8*>(&Bs[0][sn][sh + 8]) = *reinterpret_cast<const short8*>(p0 + 8);
            *reinterpret_cast<short8*>(&Bs[1][sn][sh + 0]) = *reinterpret_cast<const short8*>(p1);
            *reinterpret_cast<short8*>(&Bs[1][sn][sh + 8]) = *reinterpret_cast<const short8*>(p1 + 8);
        }
        // A fragment lane-direct from global (fp32 -> bf16)
        float4 a0 = *reinterpret_cast<const float4*>(abase + kt);
        float4 a1 = *reinterpret_cast<const float4*>(abase + kt + 4);
        short8 af;
        af[0] = f2bf(a0.x); af[1] = f2bf(a0.y); af[2] = f2bf(a0.z); af[3] = f2bf(a0.w);
        af[4] = f2bf(a1.x); af[5] = f2bf(a1.y); af[6] = f2bf(a1.z); af[7] = f2bf(a1.w);
        __syncthreads();
#pragma unroll
        for (int c = 0; c < 8; c++) {
            short8 bh = *reinterpret_cast<const short8*>(&Bs[0][(c << 4) + ln][lk << 3]);
            short8 bt = *reinterpret_cast<const short8*>(&Bs[1][(c << 4) + ln][lk << 3]);
            acch[c] = __builtin_amdgcn_mfma_f32_16x16x32_bf16(af, bh, acch[c], 0, 0, 0);
            acct[c] = __builtin_amdgcn_mfma_f32_16x16x32_bf16(af, bt, acct[c], 0, 0, 0);
        }
    }

    // -------- epilogue 1: scalars from fp32 acc; xr -> LDS bf16 --------
    float p1[4] = {0,0,0,0}, p2[4] = {0,0,0,0}, p3[4] = {0,0,0,0}, p4[4] = {0,0,0,0};
#pragma unroll
    for (int c = 0; c < 8; c++) {
        const int col = (c << 4) + ln;
        const float wa1 = ah1[col], wa2 = ah2[col], wa3 = at1[col], wa4 = at2[col];
#pragma unroll
        for (int r = 0; r < 4; r++) {
            const float vh = acch[c][r], vt = acct[c][r];
            p1[r] = fmaf(vh, wa1, p1[r]);
            p3[r] = fmaf(vh, wa3, p3[r]);
            p2[r] = fmaf(vt, wa2, p2[r]);
            p4[r] = fmaf(vt, wa4, p4[r]);
            Xs[0][orow + r][col] = f2bf(vh);
            Xs[1][orow + r][col] = f2bf(vt);
        }
    }
#pragma unroll
    for (int off = 1; off < 16; off <<= 1) {
#pragma unroll
        for (int r = 0; r < 4; r++) {
            p1[r] += __shfl_xor(p1[r], off);
            p2[r] += __shfl_xor(p2[r], off);
            p3[r] += __shfl_xor(p3[r], off);
            p4[r] += __shfl_xor(p4[r], off);
        }
    }
    if (ln == 0) {
#pragma unroll
        for (int r = 0; r < 4; r++) {
            const int grow = m0 + orow + r;
            if (grow < N) {
                s1[grow] = p1[r]; s2[grow] = p2[r];
                s3[grow] = p3[r]; s4[grow] = p4[r];
            }
        }
    }

    // -------- GEMM2: msg = xr @ {rhw,rtw}, K=128, 4 k-steps --------
    f32x4 a2h[8], a2t[8];
#pragma unroll
    for (int c = 0; c < 8; c++) {
        a2h[c] = (f32x4){0.f, 0.f, 0.f, 0.f};
        a2t[c] = (f32x4){0.f, 0.f, 0.f, 0.f};
    }
    for (int kt = 0; kt < RHD; kt += 32) {
        __syncthreads();   // also covers Xs writes (first iter) / Bs reads (prev)
        {
            const short* p0 = rhwT + (size_t)sn * RHD + kt + sh;
            const short* p1 = rtwT + (size_t)sn * RHD + kt + sh;
            *reinterpret_cast<short8*>(&Bs[0][sn][sh + 0]) = *reinterpret_cast<const short8*>(p0);
            *reinterpret_cast<short8*>(&Bs[0][sn][sh + 8]) = *reinterpret_cast<const short8*>(p0 + 8);
            *reinterpret_cast<short8*>(&Bs[1][sn][sh + 0]) = *reinterpret_cast<const short8*>(p1);
            *reinterpret_cast<short8*>(&Bs[1][sn][sh + 8]) = *reinterpret_cast<const short8*>(p1 + 8);
        }
        __syncthreads();
        short8 ah = *reinterpret_cast<const short8*>(&Xs[0][(w << 4) + ln][kt + (lk << 3)]);
        short8 av = *reinterpret_cast<const short8*>(&Xs[1][(w << 4) + ln][kt + (lk << 3)]);
#pragma unroll
        for (int c = 0; c < 8; c++) {
            short8 bh = *reinterpret_cast<const short8*>(&Bs[0][(c << 4) + ln][lk << 3]);
            short8 bt = *reinterpret_cast<const short8*>(&Bs[1][(c << 4) + ln][lk << 3]);
            a2h[c] = __builtin_amdgcn_mfma_f32_16x16x32_bf16(ah, bh, a2h[c], 0, 0, 0);
            a2t[c] = __builtin_amdgcn_mfma_f32_16x16x32_bf16(av, bt, a2t[c], 0, 0, 0);
        }
    }

    // -------- epilogue 2: msg = acc + bias + residual (fp32 out) --------
#pragma unroll
    for (int c = 0; c < 8; c++) {
        const int col = (c << 4) + ln;
        const float bh = rhb[col], bt = rtb[col];
#pragma unroll
        for (int r = 0; r < 4; r++) {
            const int grow = m0 + orow + r;
            if (grow < N) {
                msgh[(size_t)grow * RHD + col] = a2h[c][r] + bh + bf2f(Xs[0][orow + r][col]);
                msgt[(size_t)grow * RHD + col] = a2t[c][r] + bt + bf2f(Xs[1][orow + r][col]);
            }
        }
    }
}

// ---------------- CSR sort by relation --------------------------------------
__global__ void k_hist(const int* __restrict__ rel, int* __restrict__ counts, int E)
{
    int e = blockIdx.x * blockDim.x + threadIdx.x;
    if (e < E) atomicAdd(&counts[rel[e]], 1);
}

__global__ __launch_bounds__(1024) void k_scan(
    const int* __restrict__ counts, int* __restrict__ starts,
    int* __restrict__ cursor, int R, int E)
{
    __shared__ int buf[2][1024];
    int t = threadIdx.x;
    int v = (t < R) ? counts[t] : 0;
    buf[0][t] = v;
    int cur = 0;
    for (int off = 1; off < 1024; off <<= 1) {
        __syncthreads();
        int x = buf[cur][t];
        if (t >= off) x += buf[cur][t - off];
        buf[cur ^ 1][t] = x;
        cur ^= 1;
    }
    __syncthreads();
    int incl = buf[cur][t];
    if (t < R) { starts[t] = incl - v; cursor[t] = incl - v; }
    if (t == 0) starts[R] = E;
}

__global__ void k_scatter(const int* __restrict__ rel, int* __restrict__ cursor,
                          int* __restrict__ sorted, int E)
{
    int e = blockIdx.x * blockDim.x + threadIdx.x;
    if (e < E) {
        int pos = atomicAdd(&cursor[rel[e]], 1);
        sorted[pos] = e;
    }
}

// ---------------- per-relation softmax + weighted reduce --------------------
__global__ __launch_bounds__(256) void k_rel(
    const int* __restrict__ sorted, const int* __restrict__ starts,
    const int* __restrict__ eh, const int* __restrict__ et,
    const float* __restrict__ s1, const float* __restrict__ s2,
    const float* __restrict__ s3, const float* __restrict__ s4,
    const float* __restrict__ msgh, const float* __restrict__ msgt,
    float* __restrict__ out)
{
    const int r = blockIdx.x;
    const int start = starts[r], end = starts[r + 1];
    const int tid = threadIdx.x;
    if (start >= end) {
        if (tid < 128) out[(size_t)r * RHD + tid] = 0.f;
        return;
    }
    __shared__ float red[8];

    float m1 = -INFINITY, m2 = -INFINITY;
    for (int i = start + tid; i < end; i += 256) {
        int e = sorted[i];
        int h = eh[e], t = et[e];
        float e1 = leaky(s1[h] + s2[t]);
        float e2 = leaky(s3[h] + s4[t]);
        m1 = fmaxf(m1, e1); m2 = fmaxf(m2, e2);
    }
#pragma unroll
    for (int off = 32; off > 0; off >>= 1) {
        m1 = fmaxf(m1, __shfl_xor(m1, off));
        m2 = fmaxf(m2, __shfl_xor(m2, off));
    }
    const int w = tid >> 6;
    if ((tid & 63) == 0) { red[w * 2] = m1; red[w * 2 + 1] = m2; }
    __syncthreads();
    m1 = fmaxf(fmaxf(red[0], red[2]), fmaxf(red[4], red[6]));
    m2 = fmaxf(fmaxf(red[1], red[3]), fmaxf(red[5], red[7]));
    __syncthreads();

    float sum1 = 0.f, sum2 = 0.f;
    for (int i = start + tid; i < end; i += 256) {
        int e = sorted[i];
        int h = eh[e], t = et[e];
        float e1 = leaky(s1[h] + s2[t]);
        float e2 = leaky(s3[h] + s4[t]);
        sum1 += __expf(e1 - m1);
        sum2 += __expf(e2 - m2);
    }
#pragma unroll
    for (int off = 32; off > 0; off >>= 1) {
        sum1 += __shfl_xor(sum1, off);
        sum2 += __shfl_xor(sum2, off);
    }
    if ((tid & 63) == 0) { red[w * 2] = sum1; red[w * 2 + 1] = sum2; }
    __syncthreads();
    sum1 = red[0] + red[2] + red[4] + red[6];
    sum2 = red[1] + red[3] + red[5] + red[7];
    const float inv1 = 1.f / sum1, inv2 = 1.f / sum2;

    __shared__ float alph[2][256];
    __shared__ int   nds[2][256];
    const int j = tid & 127;
    const int side = tid >> 7;
    const float* __restrict__ mbase = side ? msgt : msgh;
    float a0 = 0.f, a1 = 0.f, a2 = 0.f, a3 = 0.f;

    for (int c0 = start; c0 < end; c0 += 256) {
        __syncthreads();
        int i = c0 + tid;
        if (i < end) {
            int e = sorted[i];
            int h = eh[e], t = et[e];
            float e1 = leaky(s1[h] + s2[t]);
            float e2 = leaky(s3[h] + s4[t]);
            alph[0][tid] = __expf(e1 - m1) * inv1;
            alph[1][tid] = __expf(e2 - m2) * inv2;
            nds[0][tid] = h; nds[1][tid] = t;
        }
        __syncthreads();
        const int nc = min(256, end - c0);
        int q = 0;
        for (; q + 4 <= nc; q += 4) {
            float w0 = alph[side][q + 0]; int n0 = nds[side][q + 0];
            float w1 = alph[side][q + 1]; int n1 = nds[side][q + 1];
            float w2 = alph[side][q + 2]; int n2 = nds[side][q + 2];
            float w3 = alph[side][q + 3]; int n3 = nds[side][q + 3];
            a0 = fmaf(w0, mbase[(size_t)n0 * RHD + j], a0);
            a1 = fmaf(w1, mbase[(size_t)n1 * RHD + j], a1);
            a2 = fmaf(w2, mbase[(size_t)n2 * RHD + j], a2);
            a3 = fmaf(w3, mbase[(size_t)n3 * RHD + j], a3);
        }
        for (; q < nc; q++)
            a0 = fmaf(alph[side][q], mbase[(size_t)nds[side][q] * RHD + j], a0);
    }
    float acc = a0 + a1 + a2 + a3;

    __shared__ float comb[128];
    __syncthreads();
    if (side) comb[j] = acc;
    __syncthreads();
    if (!side) out[(size_t)r * RHD + j] = acc + comb[j];
}

// ---------------------------------------------------------------------------
extern "C" void kernel_launch(void* const* d_in, const int* in_sizes, int n_in,
                              void* d_out, int out_size, void* d_ws, size_t ws_size,
                              hipStream_t stream)
{
    const float* xe  = (const float*)d_in[0];
    const int*  eidx = (const int*)d_in[1];
    const int*  rel  = (const int*)d_in[2];
    const float* wh  = (const float*)d_in[4];
    const float* wt  = (const float*)d_in[5];
    const float* ah1 = (const float*)d_in[6];
    const float* ah2 = (const float*)d_in[7];
    const float* at1 = (const float*)d_in[8];
    const float* at2 = (const float*)d_in[9];
    const float* rhw = (const float*)d_in[10];
    const float* rhb = (const float*)d_in[11];
    const float* rtw = (const float*)d_in[12];
    const float* rtb = (const float*)d_in[13];
    float* out = (float*)d_out;

    const int N = in_sizes[0] / EHD;
    const int E = in_sizes[2];
    const int R = out_size / RHD;
    const int* eh = eidx;
    const int* et = eidx + E;

    char* ws = (char*)d_ws;
    size_t off = 0;
    auto alloc = [&](size_t bytes) -> void* {
        void* p = ws + off;
        off = (off + bytes + 255) & ~(size_t)255;
        return p;
    };
    float* msgh  = (float*)alloc((size_t)N * RHD * sizeof(float));
    float* msgt  = (float*)alloc((size_t)N * RHD * sizeof(float));
    short* whT   = (short*)alloc((size_t)RHD * EHD * sizeof(short));
    short* wtT   = (short*)alloc((size_t)RHD * EHD * sizeof(short));
    short* rhwT  = (short*)alloc((size_t)RHD * RHD * sizeof(short));
    short* rtwT  = (short*)alloc((size_t)RHD * RHD * sizeof(short));
    float* s1    = (float*)alloc((size_t)N * sizeof(float));
    float* s2    = (float*)alloc((size_t)N * sizeof(float));
    float* s3    = (float*)alloc((size_t)N * sizeof(float));
    float* s4    = (float*)alloc((size_t)N * sizeof(float));
    int* counts  = (int*)alloc((size_t)R * sizeof(int));
    int* starts  = (int*)alloc((size_t)(R + 1) * sizeof(int));
    int* cursor  = (int*)alloc((size_t)R * sizeof(int));
    int* sorted  = (int*)alloc((size_t)E * sizeof(int));
    (void)ws_size; (void)n_in;

    hipMemsetAsync(counts, 0, (size_t)R * sizeof(int), stream);

    k_prep<<<dim3(EHD / 32, RHD / 32), 256, 0, stream>>>(wh, whT, EHD, RHD);
    k_prep<<<dim3(EHD / 32, RHD / 32), 256, 0, stream>>>(wt, wtT, EHD, RHD);
    k_prep<<<dim3(RHD / 32, RHD / 32), 256, 0, stream>>>(rhw, rhwT, RHD, RHD);
    k_prep<<<dim3(RHD / 32, RHD / 32), 256, 0, stream>>>(rtw, rtwT, RHD, RHD);

    k_fused<<<(N + 63) / 64, 256, 0, stream>>>(
        xe, whT, wtT, rhwT, rtwT, rhb, rtb, ah1, ah2, at1, at2,
        s1, s2, s3, s4, msgh, msgt, N);

    k_hist<<<(E + 255) / 256, 256, 0, stream>>>(rel, counts, E);
    k_scan<<<1, 1024, 0, stream>>>(counts, starts, cursor, R, E);
    k_scatter<<<(E + 255) / 256, 256, 0, stream>>>(rel, cursor, sorted, E);
    k_rel<<<R, 256, 0, stream>>>(sorted, starts, eh, et, s1, s2, s3, s4,
                                 msgh, msgt, out);
}

// Round 3
// 263.403 us; speedup vs baseline: 2.3597x; 1.6471x over previous
//
#include <hip/hip_runtime.h>
#include <hip/hip_bf16.h>
#include <math.h>

// ---------------------------------------------------------------------------
// GAT_E_to_R: N=100000, E=500000, EH=256, RH=128, R=1000
// Dense pipeline fused into one bf16-MFMA kernel (msg stored bf16);
// edge phase: CSR sort by relation with logits precomputed at scatter,
// per-(relation,side) softmax+reduce blocks.
// ---------------------------------------------------------------------------

#define EHD 256
#define RHD 128
#define BSTR 40    // Bs row stride in shorts
#define XSTR 136   // Xs row stride in shorts (272B, 16B-aligned)
#define RMAX 1024

typedef __attribute__((ext_vector_type(8))) short short8;
typedef __attribute__((ext_vector_type(4))) float f32x4;

__device__ __forceinline__ short f2bf(float x) {
    __hip_bfloat16 b = __float2bfloat16(x);   // RNE
    return *reinterpret_cast<short*>(&b);
}
__device__ __forceinline__ float bf2f(short s) {
    __hip_bfloat16 b = *reinterpret_cast<__hip_bfloat16*>(&s);
    return __bfloat162float(b);
}
__device__ __forceinline__ float bfu(unsigned int u) {
    return __uint_as_float(u << 16);
}
__device__ __forceinline__ float leaky(float x) { return x > 0.f ? x : 0.01f * x; }

// ---- transpose+convert: dst[n][k] (bf16) = src[k][n] (fp32) ----------------
__global__ __launch_bounds__(256) void k_prep(const float* __restrict__ src,
                                              short* __restrict__ dst,
                                              int K, int Nc)
{
    __shared__ float t[32][33];
    const int k0 = blockIdx.x * 32, n0 = blockIdx.y * 32;
    const int tr = threadIdx.x >> 3, tc = (threadIdx.x & 7) << 2;
    float4 v = *reinterpret_cast<const float4*>(src + (size_t)(k0 + tr) * Nc + n0 + tc);
    t[tr][tc + 0] = v.x; t[tr][tc + 1] = v.y;
    t[tr][tc + 2] = v.z; t[tr][tc + 3] = v.w;
    __syncthreads();
    short* o = dst + (size_t)(n0 + tr) * K + k0 + tc;
    o[0] = f2bf(t[tc + 0][tr]); o[1] = f2bf(t[tc + 1][tr]);
    o[2] = f2bf(t[tc + 2][tr]); o[3] = f2bf(t[tc + 3][tr]);
}

// ---- fused: xr = xe@{wh,wt}; s1..s4; msg(bf16) = xr@{rhw,rtw} + b + xr ------
__global__ __launch_bounds__(256, 2) void k_fused(
    const float* __restrict__ xe,
    const short* __restrict__ whT, const short* __restrict__ wtT,   // [128][256]
    const short* __restrict__ rhwT, const short* __restrict__ rtwT, // [128][128]
    const float* __restrict__ rhb, const float* __restrict__ rtb,
    const float* __restrict__ ah1, const float* __restrict__ ah2,
    const float* __restrict__ at1, const float* __restrict__ at2,
    float* __restrict__ s1, float* __restrict__ s2,
    float* __restrict__ s3, float* __restrict__ s4,
    short* __restrict__ msgh, short* __restrict__ msgt, int N)
{
    __shared__ __align__(16) short Bs[2][128][BSTR];   // 20480 B
    __shared__ __align__(16) short Xs[2][64][XSTR];    // 34816 B

    const int tid = threadIdx.x;
    const int w = tid >> 6, l = tid & 63;
    const int ln = l & 15, lk = l >> 4;
    const int m0 = blockIdx.x * 64;
    const int sn = tid >> 1, sh = (tid & 1) << 4;
    const int orow = (w << 4) + (lk << 2);

    f32x4 acch[8], acct[8];
#pragma unroll
    for (int c = 0; c < 8; c++) {
        acch[c] = (f32x4){0.f, 0.f, 0.f, 0.f};
        acct[c] = (f32x4){0.f, 0.f, 0.f, 0.f};
    }

    // -------- GEMM1: K=256, 8 k-steps --------
    const int arow = m0 + (w << 4) + ln;
    const int aclamp = min(arow, N - 1);
    const float* abase = xe + (size_t)aclamp * EHD + (lk << 3);

    for (int kt = 0; kt < EHD; kt += 32) {
        __syncthreads();
        {
            const short* p0 = whT + (size_t)sn * EHD + kt + sh;
            const short* p1 = wtT + (size_t)sn * EHD + kt + sh;
            *reinterpret_cast<short8*>(&Bs[0][sn][sh + 0]) = *reinterpret_cast<const short8*>(p0);
            *reinterpret_cast<short8*>(&Bs[0][sn][sh + 8]) = *reinterpret_cast<const short8*>(p0 + 8);
            *reinterpret_cast<short8*>(&Bs[1][sn][sh + 0]) = *reinterpret_cast<const short8*>(p1);
            *reinterpret_cast<short8*>(&Bs[1][sn][sh + 8]) = *reinterpret_cast<const short8*>(p1 + 8);
        }
        float4 a0 = *reinterpret_cast<const float4*>(abase + kt);
        float4 a1 = *reinterpret_cast<const float4*>(abase + kt + 4);
        short8 af;
        af[0] = f2bf(a0.x); af[1] = f2bf(a0.y); af[2] = f2bf(a0.z); af[3] = f2bf(a0.w);
        af[4] = f2bf(a1.x); af[5] = f2bf(a1.y); af[6] = f2bf(a1.z); af[7] = f2bf(a1.w);
        __syncthreads();
#pragma unroll
        for (int c = 0; c < 8; c++) {
            short8 bh = *reinterpret_cast<const short8*>(&Bs[0][(c << 4) + ln][lk << 3]);
            short8 bt = *reinterpret_cast<const short8*>(&Bs[1][(c << 4) + ln][lk << 3]);
            acch[c] = __builtin_amdgcn_mfma_f32_16x16x32_bf16(af, bh, acch[c], 0, 0, 0);
            acct[c] = __builtin_amdgcn_mfma_f32_16x16x32_bf16(af, bt, acct[c], 0, 0, 0);
        }
    }

    // -------- epilogue 1: scalars from fp32 acc; xr -> LDS bf16 --------
    float p1[4] = {0,0,0,0}, p2[4] = {0,0,0,0}, p3[4] = {0,0,0,0}, p4[4] = {0,0,0,0};
#pragma unroll
    for (int c = 0; c < 8; c++) {
        const int col = (c << 4) + ln;
        const float wa1 = ah1[col], wa2 = ah2[col], wa3 = at1[col], wa4 = at2[col];
#pragma unroll
        for (int r = 0; r < 4; r++) {
            const float vh = acch[c][r], vt = acct[c][r];
            p1[r] = fmaf(vh, wa1, p1[r]);
            p3[r] = fmaf(vh, wa3, p3[r]);
            p2[r] = fmaf(vt, wa2, p2[r]);
            p4[r] = fmaf(vt, wa4, p4[r]);
            Xs[0][orow + r][col] = f2bf(vh);
            Xs[1][orow + r][col] = f2bf(vt);
        }
    }
#pragma unroll
    for (int off = 1; off < 16; off <<= 1) {
#pragma unroll
        for (int r = 0; r < 4; r++) {
            p1[r] += __shfl_xor(p1[r], off);
            p2[r] += __shfl_xor(p2[r], off);
            p3[r] += __shfl_xor(p3[r], off);
            p4[r] += __shfl_xor(p4[r], off);
        }
    }
    if (ln == 0) {
#pragma unroll
        for (int r = 0; r < 4; r++) {
            const int grow = m0 + orow + r;
            if (grow < N) {
                s1[grow] = p1[r]; s2[grow] = p2[r];
                s3[grow] = p3[r]; s4[grow] = p4[r];
            }
        }
    }

    // -------- GEMM2: msg = xr @ {rhw,rtw}, K=128, 4 k-steps --------
    f32x4 a2h[8], a2t[8];
#pragma unroll
    for (int c = 0; c < 8; c++) {
        a2h[c] = (f32x4){0.f, 0.f, 0.f, 0.f};
        a2t[c] = (f32x4){0.f, 0.f, 0.f, 0.f};
    }
    for (int kt = 0; kt < RHD; kt += 32) {
        __syncthreads();
        {
            const short* p0 = rhwT + (size_t)sn * RHD + kt + sh;
            const short* p1 = rtwT + (size_t)sn * RHD + kt + sh;
            *reinterpret_cast<short8*>(&Bs[0][sn][sh + 0]) = *reinterpret_cast<const short8*>(p0);
            *reinterpret_cast<short8*>(&Bs[0][sn][sh + 8]) = *reinterpret_cast<const short8*>(p0 + 8);
            *reinterpret_cast<short8*>(&Bs[1][sn][sh + 0]) = *reinterpret_cast<const short8*>(p1);
            *reinterpret_cast<short8*>(&Bs[1][sn][sh + 8]) = *reinterpret_cast<const short8*>(p1 + 8);
        }
        __syncthreads();
        short8 ahf = *reinterpret_cast<const short8*>(&Xs[0][(w << 4) + ln][kt + (lk << 3)]);
        short8 avf = *reinterpret_cast<const short8*>(&Xs[1][(w << 4) + ln][kt + (lk << 3)]);
#pragma unroll
        for (int c = 0; c < 8; c++) {
            short8 bh = *reinterpret_cast<const short8*>(&Bs[0][(c << 4) + ln][lk << 3]);
            short8 bt = *reinterpret_cast<const short8*>(&Bs[1][(c << 4) + ln][lk << 3]);
            a2h[c] = __builtin_amdgcn_mfma_f32_16x16x32_bf16(ahf, bh, a2h[c], 0, 0, 0);
            a2t[c] = __builtin_amdgcn_mfma_f32_16x16x32_bf16(avf, bt, a2t[c], 0, 0, 0);
        }
    }

    // -------- epilogue 2: msg = acc + bias + residual -> bf16 via Xs --------
#pragma unroll
    for (int c = 0; c < 8; c++) {
        const int col = (c << 4) + ln;
        const float bh = rhb[col], bt = rtb[col];
#pragma unroll
        for (int r = 0; r < 4; r++) {
            a2h[c][r] += bh + bf2f(Xs[0][orow + r][col]);
            a2t[c][r] += bt + bf2f(Xs[1][orow + r][col]);
        }
    }
    __syncthreads();   // everyone done reading Xs (residual)
#pragma unroll
    for (int c = 0; c < 8; c++) {
        const int col = (c << 4) + ln;
#pragma unroll
        for (int r = 0; r < 4; r++) {
            Xs[0][orow + r][col] = f2bf(a2h[c][r]);
            Xs[1][orow + r][col] = f2bf(a2t[c][r]);
        }
    }
    __syncthreads();
    // coalesced short8 stores: 2048 chunks (2 mats x 64 rows x 16), 8/thread
#pragma unroll
    for (int it = 0; it < 8; it++) {
        const int idx = tid + (it << 8);
        const int mat = idx >> 10;
        const int rem = idx & 1023;
        const int row = rem >> 4;
        const int ch  = rem & 15;
        const int grow = m0 + row;
        if (grow < N) {
            short8 v = *reinterpret_cast<const short8*>(&Xs[mat][row][ch << 3]);
            short* dst = (mat ? msgt : msgh) + (size_t)grow * RHD + (ch << 3);
            *reinterpret_cast<short8*>(dst) = v;
        }
    }
}

// ---------------- CSR sort by relation --------------------------------------
__global__ __launch_bounds__(256) void k_hist(const int* __restrict__ rel,
                                              int* __restrict__ counts, int R, int E)
{
    __shared__ int cnt[RMAX];
    for (int i = threadIdx.x; i < R; i += 256) cnt[i] = 0;
    __syncthreads();
    for (int e = blockIdx.x * 256 + threadIdx.x; e < E; e += gridDim.x * 256)
        atomicAdd(&cnt[rel[e]], 1);
    __syncthreads();
    for (int i = threadIdx.x; i < R; i += 256) {
        int v = cnt[i];
        if (v) atomicAdd(&counts[i], v);
    }
}

__global__ __launch_bounds__(1024) void k_scan(
    const int* __restrict__ counts, int* __restrict__ starts,
    int* __restrict__ cursor, int R, int E)
{
    __shared__ int buf[2][1024];
    int t = threadIdx.x;
    int v = (t < R) ? counts[t] : 0;
    buf[0][t] = v;
    int cur = 0;
    for (int off = 1; off < 1024; off <<= 1) {
        __syncthreads();
        int x = buf[cur][t];
        if (t >= off) x += buf[cur][t - off];
        buf[cur ^ 1][t] = x;
        cur ^= 1;
    }
    __syncthreads();
    int incl = buf[cur][t];
    if (t < R) { starts[t] = incl - v; cursor[t] = incl - v; }
    if (t == 0) starts[R] = E;
}

// scatter + precompute logits into sorted order
__global__ void k_scatter(const int* __restrict__ rel, int* __restrict__ cursor,
                          const int* __restrict__ eh, const int* __restrict__ et,
                          const float* __restrict__ s1, const float* __restrict__ s2,
                          const float* __restrict__ s3, const float* __restrict__ s4,
                          int* __restrict__ hs, int* __restrict__ ts,
                          float* __restrict__ e1s, float* __restrict__ e2s, int E)
{
    int e = blockIdx.x * blockDim.x + threadIdx.x;
    if (e < E) {
        int r = rel[e];
        int pos = atomicAdd(&cursor[r], 1);
        int h = eh[e], t = et[e];
        hs[pos] = h; ts[pos] = t;
        e1s[pos] = leaky(s1[h] + s2[t]);
        e2s[pos] = leaky(s3[h] + s4[t]);
    }
}

// ---------------- per-(relation,side) softmax + weighted reduce -------------
__global__ __launch_bounds__(256) void k_rel(
    const int* __restrict__ starts,
    const int* __restrict__ hs, const int* __restrict__ ts,
    const float* __restrict__ e1s, const float* __restrict__ e2s,
    const short* __restrict__ msgh, const short* __restrict__ msgt,
    float* __restrict__ out)
{
    const int r = blockIdx.x;
    const int side = blockIdx.y;
    const int start = starts[r], end = starts[r + 1];
    if (start >= end) return;                    // out pre-zeroed
    const int tid = threadIdx.x;
    const float* __restrict__ es = side ? e2s : e1s;
    const int*   __restrict__ ns = side ? ts : hs;
    const unsigned short* __restrict__ mb =
        reinterpret_cast<const unsigned short*>(side ? msgt : msgh);

    __shared__ float red[8];

    // pass 1: max
    float m = -INFINITY;
    for (int i = start + tid; i < end; i += 256) m = fmaxf(m, es[i]);
#pragma unroll
    for (int off = 32; off > 0; off >>= 1) m = fmaxf(m, __shfl_xor(m, off));
    if ((tid & 63) == 0) red[tid >> 6] = m;
    __syncthreads();
    m = fmaxf(fmaxf(red[0], red[1]), fmaxf(red[2], red[3]));
    __syncthreads();

    // pass 2: sum(exp)
    float sum = 0.f;
    for (int i = start + tid; i < end; i += 256) sum += __expf(es[i] - m);
#pragma unroll
    for (int off = 32; off > 0; off >>= 1) sum += __shfl_xor(sum, off);
    if ((tid & 63) == 0) red[4 + (tid >> 6)] = sum;
    __syncthreads();
    sum = red[4] + red[5] + red[6] + red[7];
    const float inv = 1.f / sum;

    // pass 3: weighted accumulate. wave w handles edges q (q%4==w), all 128 cols.
    __shared__ float al[256];
    __shared__ int   nd[256];
    const int slot = tid >> 6;        // wave id
    const int jj = tid & 63;          // column pair
    float a0 = 0.f, a1 = 0.f;

    for (int c0 = start; c0 < end; c0 += 256) {
        __syncthreads();
        int i = c0 + tid;
        if (i < end) {
            al[tid] = __expf(es[i] - m) * inv;
            nd[tid] = ns[i];
        }
        __syncthreads();
        const int nc = min(256, end - c0);
        for (int q = slot; q < nc; q += 4) {
            const float wq = al[q];
            const int n = nd[q];
            const unsigned int v =
                *reinterpret_cast<const unsigned int*>(mb + (size_t)n * RHD + (jj << 1));
            a0 = fmaf(wq, bfu(v & 0xffffu), a0);
            a1 = fmaf(wq, bfu(v >> 16), a1);
        }
    }

    __shared__ float part[4][128];
    part[slot][(jj << 1) + 0] = a0;
    part[slot][(jj << 1) + 1] = a1;
    __syncthreads();
    if (tid < 128) {
        float v = part[0][tid] + part[1][tid] + part[2][tid] + part[3][tid];
        atomicAdd(&out[(size_t)r * RHD + tid], v);
    }
}

// ---------------------------------------------------------------------------
extern "C" void kernel_launch(void* const* d_in, const int* in_sizes, int n_in,
                              void* d_out, int out_size, void* d_ws, size_t ws_size,
                              hipStream_t stream)
{
    const float* xe  = (const float*)d_in[0];
    const int*  eidx = (const int*)d_in[1];
    const int*  rel  = (const int*)d_in[2];
    const float* wh  = (const float*)d_in[4];
    const float* wt  = (const float*)d_in[5];
    const float* ah1 = (const float*)d_in[6];
    const float* ah2 = (const float*)d_in[7];
    const float* at1 = (const float*)d_in[8];
    const float* at2 = (const float*)d_in[9];
    const float* rhw = (const float*)d_in[10];
    const float* rhb = (const float*)d_in[11];
    const float* rtw = (const float*)d_in[12];
    const float* rtb = (const float*)d_in[13];
    float* out = (float*)d_out;

    const int N = in_sizes[0] / EHD;
    const int E = in_sizes[2];
    const int R = out_size / RHD;
    const int* eh = eidx;
    const int* et = eidx + E;

    char* ws = (char*)d_ws;
    size_t off = 0;
    auto alloc = [&](size_t bytes) -> void* {
        void* p = ws + off;
        off = (off + bytes + 255) & ~(size_t)255;
        return p;
    };
    short* msgh  = (short*)alloc((size_t)N * RHD * sizeof(short));
    short* msgt  = (short*)alloc((size_t)N * RHD * sizeof(short));
    short* whT   = (short*)alloc((size_t)RHD * EHD * sizeof(short));
    short* wtT   = (short*)alloc((size_t)RHD * EHD * sizeof(short));
    short* rhwT  = (short*)alloc((size_t)RHD * RHD * sizeof(short));
    short* rtwT  = (short*)alloc((size_t)RHD * RHD * sizeof(short));
    float* s1    = (float*)alloc((size_t)N * sizeof(float));
    float* s2    = (float*)alloc((size_t)N * sizeof(float));
    float* s3    = (float*)alloc((size_t)N * sizeof(float));
    float* s4    = (float*)alloc((size_t)N * sizeof(float));
    int* counts  = (int*)alloc((size_t)R * sizeof(int));
    int* starts  = (int*)alloc((size_t)(R + 1) * sizeof(int));
    int* cursor  = (int*)alloc((size_t)R * sizeof(int));
    int* hs      = (int*)alloc((size_t)E * sizeof(int));
    int* ts      = (int*)alloc((size_t)E * sizeof(int));
    float* e1s   = (float*)alloc((size_t)E * sizeof(float));
    float* e2s   = (float*)alloc((size_t)E * sizeof(float));
    (void)ws_size; (void)n_in;

    hipMemsetAsync(counts, 0, (size_t)R * sizeof(int), stream);
    hipMemsetAsync(out, 0, (size_t)out_size * sizeof(float), stream);

    k_prep<<<dim3(EHD / 32, RHD / 32), 256, 0, stream>>>(wh, whT, EHD, RHD);
    k_prep<<<dim3(EHD / 32, RHD / 32), 256, 0, stream>>>(wt, wtT, EHD, RHD);
    k_prep<<<dim3(RHD / 32, RHD / 32), 256, 0, stream>>>(rhw, rhwT, RHD, RHD);
    k_prep<<<dim3(RHD / 32, RHD / 32), 256, 0, stream>>>(rtw, rtwT, RHD, RHD);

    k_fused<<<(N + 63) / 64, 256, 0, stream>>>(
        xe, whT, wtT, rhwT, rtwT, rhb, rtb, ah1, ah2, at1, at2,
        s1, s2, s3, s4, msgh, msgt, N);

    k_hist<<<128, 256, 0, stream>>>(rel, counts, R, E);
    k_scan<<<1, 1024, 0, stream>>>(counts, starts, cursor, R, E);
    k_scatter<<<(E + 255) / 256, 256, 0, stream>>>(rel, cursor, eh, et,
                                                   s1, s2, s3, s4,
                                                   hs, ts, e1s, e2s, E);
    k_rel<<<dim3(R, 2), 256, 0, stream>>>(starts, hs, ts, e1s, e2s,
                                          msgh, msgt, out);
}

// Round 4
// 183.430 us; speedup vs baseline: 3.3885x; 1.4360x over previous
//
#include <hip/hip_runtime.h>
#include <hip/hip_bf16.h>
#include <math.h>

// ---------------------------------------------------------------------------
// GAT_E_to_R: N=100000, E=500000, EH=256, RH=128, R=1000
// Dense pipeline fused into one bf16-MFMA kernel (msg stored bf16);
// edge phase: block-privatized CSR scatter into packed records,
// per-(relation,side) softmax+reduce with LDS-cached segments.
// ---------------------------------------------------------------------------

#define EHD 256
#define RHD 128
#define BSTR 40     // Bs row stride in shorts
#define XSTR 136    // Xs row stride in shorts (272B, 16B-aligned)
#define RMAX 1024
#define SCHUNK 2048 // edges per scatter block
#define SEGMAX 4096 // max cached segment length in k_rel

typedef __attribute__((ext_vector_type(8))) short short8;
typedef __attribute__((ext_vector_type(4))) float f32x4;

__device__ __forceinline__ short f2bf(float x) {
    __hip_bfloat16 b = __float2bfloat16(x);   // RNE
    return *reinterpret_cast<short*>(&b);
}
__device__ __forceinline__ float bf2f(short s) {
    __hip_bfloat16 b = *reinterpret_cast<__hip_bfloat16*>(&s);
    return __bfloat162float(b);
}
__device__ __forceinline__ float bfu(unsigned int u) {
    return __uint_as_float(u << 16);
}
__device__ __forceinline__ float leaky(float x) { return x > 0.f ? x : 0.01f * x; }

// ---- transpose+convert: dst[n][k] (bf16) = src[k][n] (fp32) ----------------
__global__ __launch_bounds__(256) void k_prep(const float* __restrict__ src,
                                              short* __restrict__ dst,
                                              int K, int Nc)
{
    __shared__ float t[32][33];
    const int k0 = blockIdx.x * 32, n0 = blockIdx.y * 32;
    const int tr = threadIdx.x >> 3, tc = (threadIdx.x & 7) << 2;
    float4 v = *reinterpret_cast<const float4*>(src + (size_t)(k0 + tr) * Nc + n0 + tc);
    t[tr][tc + 0] = v.x; t[tr][tc + 1] = v.y;
    t[tr][tc + 2] = v.z; t[tr][tc + 3] = v.w;
    __syncthreads();
    short* o = dst + (size_t)(n0 + tr) * K + k0 + tc;
    o[0] = f2bf(t[tc + 0][tr]); o[1] = f2bf(t[tc + 1][tr]);
    o[2] = f2bf(t[tc + 2][tr]); o[3] = f2bf(t[tc + 3][tr]);
}

// ---- fused: xr = xe@{wh,wt}; s1..s4; msg(bf16) = xr@{rhw,rtw} + b + xr ------
__global__ __launch_bounds__(256, 2) void k_fused(
    const float* __restrict__ xe,
    const short* __restrict__ whT, const short* __restrict__ wtT,   // [128][256]
    const short* __restrict__ rhwT, const short* __restrict__ rtwT, // [128][128]
    const float* __restrict__ rhb, const float* __restrict__ rtb,
    const float* __restrict__ ah1, const float* __restrict__ ah2,
    const float* __restrict__ at1, const float* __restrict__ at2,
    float* __restrict__ s1, float* __restrict__ s2,
    float* __restrict__ s3, float* __restrict__ s4,
    short* __restrict__ msgh, short* __restrict__ msgt, int N)
{
    __shared__ __align__(16) short Bs[2][128][BSTR];   // 20480 B
    __shared__ __align__(16) short Xs[2][64][XSTR];    // 34816 B

    const int tid = threadIdx.x;
    const int w = tid >> 6, l = tid & 63;
    const int ln = l & 15, lk = l >> 4;
    const int m0 = blockIdx.x * 64;
    const int sn = tid >> 1, sh = (tid & 1) << 4;
    const int orow = (w << 4) + (lk << 2);

    f32x4 acch[8], acct[8];
#pragma unroll
    for (int c = 0; c < 8; c++) {
        acch[c] = (f32x4){0.f, 0.f, 0.f, 0.f};
        acct[c] = (f32x4){0.f, 0.f, 0.f, 0.f};
    }

    // -------- GEMM1: K=256, 8 k-steps --------
    const int arow = m0 + (w << 4) + ln;
    const int aclamp = min(arow, N - 1);
    const float* abase = xe + (size_t)aclamp * EHD + (lk << 3);

    for (int kt = 0; kt < EHD; kt += 32) {
        __syncthreads();
        {
            const short* p0 = whT + (size_t)sn * EHD + kt + sh;
            const short* p1 = wtT + (size_t)sn * EHD + kt + sh;
            *reinterpret_cast<short8*>(&Bs[0][sn][sh + 0]) = *reinterpret_cast<const short8*>(p0);
            *reinterpret_cast<short8*>(&Bs[0][sn][sh + 8]) = *reinterpret_cast<const short8*>(p0 + 8);
            *reinterpret_cast<short8*>(&Bs[1][sn][sh + 0]) = *reinterpret_cast<const short8*>(p1);
            *reinterpret_cast<short8*>(&Bs[1][sn][sh + 8]) = *reinterpret_cast<const short8*>(p1 + 8);
        }
        float4 a0 = *reinterpret_cast<const float4*>(abase + kt);
        float4 a1 = *reinterpret_cast<const float4*>(abase + kt + 4);
        short8 af;
        af[0] = f2bf(a0.x); af[1] = f2bf(a0.y); af[2] = f2bf(a0.z); af[3] = f2bf(a0.w);
        af[4] = f2bf(a1.x); af[5] = f2bf(a1.y); af[6] = f2bf(a1.z); af[7] = f2bf(a1.w);
        __syncthreads();
#pragma unroll
        for (int c = 0; c < 8; c++) {
            short8 bh = *reinterpret_cast<const short8*>(&Bs[0][(c << 4) + ln][lk << 3]);
            short8 bt = *reinterpret_cast<const short8*>(&Bs[1][(c << 4) + ln][lk << 3]);
            acch[c] = __builtin_amdgcn_mfma_f32_16x16x32_bf16(af, bh, acch[c], 0, 0, 0);
            acct[c] = __builtin_amdgcn_mfma_f32_16x16x32_bf16(af, bt, acct[c], 0, 0, 0);
        }
    }

    // -------- epilogue 1: scalars from fp32 acc; xr -> LDS bf16 --------
    float p1[4] = {0,0,0,0}, p2[4] = {0,0,0,0}, p3[4] = {0,0,0,0}, p4[4] = {0,0,0,0};
#pragma unroll
    for (int c = 0; c < 8; c++) {
        const int col = (c << 4) + ln;
        const float wa1 = ah1[col], wa2 = ah2[col], wa3 = at1[col], wa4 = at2[col];
#pragma unroll
        for (int r = 0; r < 4; r++) {
            const float vh = acch[c][r], vt = acct[c][r];
            p1[r] = fmaf(vh, wa1, p1[r]);
            p3[r] = fmaf(vh, wa3, p3[r]);
            p2[r] = fmaf(vt, wa2, p2[r]);
            p4[r] = fmaf(vt, wa4, p4[r]);
            Xs[0][orow + r][col] = f2bf(vh);
            Xs[1][orow + r][col] = f2bf(vt);
        }
    }
#pragma unroll
    for (int off = 1; off < 16; off <<= 1) {
#pragma unroll
        for (int r = 0; r < 4; r++) {
            p1[r] += __shfl_xor(p1[r], off);
            p2[r] += __shfl_xor(p2[r], off);
            p3[r] += __shfl_xor(p3[r], off);
            p4[r] += __shfl_xor(p4[r], off);
        }
    }
    if (ln == 0) {
#pragma unroll
        for (int r = 0; r < 4; r++) {
            const int grow = m0 + orow + r;
            if (grow < N) {
                s1[grow] = p1[r]; s2[grow] = p2[r];
                s3[grow] = p3[r]; s4[grow] = p4[r];
            }
        }
    }

    // -------- GEMM2: msg = xr @ {rhw,rtw}, K=128, 4 k-steps --------
    f32x4 a2h[8], a2t[8];
#pragma unroll
    for (int c = 0; c < 8; c++) {
        a2h[c] = (f32x4){0.f, 0.f, 0.f, 0.f};
        a2t[c] = (f32x4){0.f, 0.f, 0.f, 0.f};
    }
    for (int kt = 0; kt < RHD; kt += 32) {
        __syncthreads();
        {
            const short* p0 = rhwT + (size_t)sn * RHD + kt + sh;
            const short* p1 = rtwT + (size_t)sn * RHD + kt + sh;
            *reinterpret_cast<short8*>(&Bs[0][sn][sh + 0]) = *reinterpret_cast<const short8*>(p0);
            *reinterpret_cast<short8*>(&Bs[0][sn][sh + 8]) = *reinterpret_cast<const short8*>(p0 + 8);
            *reinterpret_cast<short8*>(&Bs[1][sn][sh + 0]) = *reinterpret_cast<const short8*>(p1);
            *reinterpret_cast<short8*>(&Bs[1][sn][sh + 8]) = *reinterpret_cast<const short8*>(p1 + 8);
        }
        __syncthreads();
        short8 ahf = *reinterpret_cast<const short8*>(&Xs[0][(w << 4) + ln][kt + (lk << 3)]);
        short8 avf = *reinterpret_cast<const short8*>(&Xs[1][(w << 4) + ln][kt + (lk << 3)]);
#pragma unroll
        for (int c = 0; c < 8; c++) {
            short8 bh = *reinterpret_cast<const short8*>(&Bs[0][(c << 4) + ln][lk << 3]);
            short8 bt = *reinterpret_cast<const short8*>(&Bs[1][(c << 4) + ln][lk << 3]);
            a2h[c] = __builtin_amdgcn_mfma_f32_16x16x32_bf16(ahf, bh, a2h[c], 0, 0, 0);
            a2t[c] = __builtin_amdgcn_mfma_f32_16x16x32_bf16(avf, bt, a2t[c], 0, 0, 0);
        }
    }

    // -------- epilogue 2: msg = acc + bias + residual -> bf16 via Xs --------
#pragma unroll
    for (int c = 0; c < 8; c++) {
        const int col = (c << 4) + ln;
        const float bh = rhb[col], bt = rtb[col];
#pragma unroll
        for (int r = 0; r < 4; r++) {
            a2h[c][r] += bh + bf2f(Xs[0][orow + r][col]);
            a2t[c][r] += bt + bf2f(Xs[1][orow + r][col]);
        }
    }
    __syncthreads();
#pragma unroll
    for (int c = 0; c < 8; c++) {
        const int col = (c << 4) + ln;
#pragma unroll
        for (int r = 0; r < 4; r++) {
            Xs[0][orow + r][col] = f2bf(a2h[c][r]);
            Xs[1][orow + r][col] = f2bf(a2t[c][r]);
        }
    }
    __syncthreads();
#pragma unroll
    for (int it = 0; it < 8; it++) {
        const int idx = tid + (it << 8);
        const int mat = idx >> 10;
        const int rem = idx & 1023;
        const int row = rem >> 4;
        const int ch  = rem & 15;
        const int grow = m0 + row;
        if (grow < N) {
            short8 v = *reinterpret_cast<const short8*>(&Xs[mat][row][ch << 3]);
            short* dst = (mat ? msgt : msgh) + (size_t)grow * RHD + (ch << 3);
            *reinterpret_cast<short8*>(dst) = v;
        }
    }
}

// ---------------- CSR sort by relation --------------------------------------
__global__ __launch_bounds__(256) void k_hist(const int* __restrict__ rel,
                                              int* __restrict__ counts, int R, int E)
{
    __shared__ int cnt[RMAX];
    for (int i = threadIdx.x; i < R; i += 256) cnt[i] = 0;
    __syncthreads();
    for (int e = blockIdx.x * 256 + threadIdx.x; e < E; e += gridDim.x * 256)
        atomicAdd(&cnt[rel[e]], 1);
    __syncthreads();
    for (int i = threadIdx.x; i < R; i += 256) {
        int v = cnt[i];
        if (v) atomicAdd(&counts[i], v);
    }
}

__global__ __launch_bounds__(1024) void k_scan(
    const int* __restrict__ counts, int* __restrict__ starts,
    int* __restrict__ cursor, int R, int E)
{
    __shared__ int buf[2][1024];
    int t = threadIdx.x;
    int v = (t < R) ? counts[t] : 0;
    buf[0][t] = v;
    int cur = 0;
    for (int off = 1; off < 1024; off <<= 1) {
        __syncthreads();
        int x = buf[cur][t];
        if (t >= off) x += buf[cur][t - off];
        buf[cur ^ 1][t] = x;
        cur ^= 1;
    }
    __syncthreads();
    int incl = buf[cur][t];
    if (t < R) { starts[t] = incl - v; cursor[t] = incl - v; }
    if (t == 0) starts[R] = E;
}

// ---- block-privatized scatter into packed records ---------------------------
// rec1[pos] = (h, e1bits), rec2[pos] = (t, e2bits); same-relation edges from
// one block land contiguously -> coalescing; 1 global atomic per (block,rel).
__global__ __launch_bounds__(256) void k_scatter(
    const int* __restrict__ rel, int* __restrict__ cursor,
    const int* __restrict__ eh, const int* __restrict__ et,
    const float* __restrict__ s1, const float* __restrict__ s2,
    const float* __restrict__ s3, const float* __restrict__ s4,
    int2* __restrict__ rec1, int2* __restrict__ rec2, int R, int E)
{
    __shared__ int lcnt[RMAX];
    __shared__ int lbase[RMAX];
    const int tid = threadIdx.x;
    const int base = blockIdx.x * SCHUNK;
    const int nE = min(SCHUNK, E - base);
    for (int i = tid; i < R; i += 256) lcnt[i] = 0;
    __syncthreads();
    for (int i = tid; i < nE; i += 256) atomicAdd(&lcnt[rel[base + i]], 1);
    __syncthreads();
    for (int r = tid; r < R; r += 256) {
        int c = lcnt[r];
        lbase[r] = c ? atomicAdd(&cursor[r], c) : 0;
        lcnt[r] = 0;
    }
    __syncthreads();
    for (int i = tid; i < nE; i += 256) {
        const int e = base + i;
        const int r = rel[e];
        const int off = atomicAdd(&lcnt[r], 1);
        const int pos = lbase[r] + off;
        const int h = eh[e], t = et[e];
        const float e1 = leaky(s1[h] + s2[t]);
        const float e2 = leaky(s3[h] + s4[t]);
        rec1[pos] = make_int2(h, __float_as_int(e1));
        rec2[pos] = make_int2(t, __float_as_int(e2));
    }
}

// ---------------- per-(relation,side) softmax + weighted reduce -------------
__global__ __launch_bounds__(256) void k_rel(
    const int* __restrict__ starts,
    const int2* __restrict__ rec1, const int2* __restrict__ rec2,
    const short* __restrict__ msgh, const short* __restrict__ msgt,
    float* __restrict__ out)
{
    const int r = blockIdx.x;
    const int side = blockIdx.y;
    const int start = starts[r], end = starts[r + 1];
    const int len = end - start;
    if (len <= 0) return;                        // out pre-zeroed
    const int tid = threadIdx.x;
    const int2* __restrict__ rc = (side ? rec2 : rec1) + start;
    const unsigned short* __restrict__ mb =
        reinterpret_cast<const unsigned short*>(side ? msgt : msgh);

    __shared__ float red[8];
    __shared__ int   lnode[SEGMAX];
    __shared__ float lal[SEGMAX];
    __shared__ float part[4][128];

    const int slot = tid >> 6;        // wave id
    const int jj = tid & 63;          // column pair
    float a0 = 0.f, a1 = 0.f;

    if (len <= SEGMAX) {
        // ---- cached path: one global read of the segment ----
        float m = -INFINITY;
        for (int i = tid; i < len; i += 256) {
            int2 v = rc[i];
            lnode[i] = v.x;
            float e = __int_as_float(v.y);
            lal[i] = e;
            m = fmaxf(m, e);
        }
#pragma unroll
        for (int off = 32; off > 0; off >>= 1) m = fmaxf(m, __shfl_xor(m, off));
        if ((tid & 63) == 0) red[slot] = m;
        __syncthreads();
        m = fmaxf(fmaxf(red[0], red[1]), fmaxf(red[2], red[3]));
        __syncthreads();

        float sum = 0.f;
        for (int i = tid; i < len; i += 256) {
            float x = __expf(lal[i] - m);
            lal[i] = x;
            sum += x;
        }
#pragma unroll
        for (int off = 32; off > 0; off >>= 1) sum += __shfl_xor(sum, off);
        if ((tid & 63) == 0) red[4 + slot] = sum;
        __syncthreads();
        sum = red[4] + red[5] + red[6] + red[7];
        const float inv = 1.f / sum;

        // accumulate: wave `slot` takes edges q = slot, slot+4, ... (LDS broadcast)
        int q = slot;
        for (; q + 4 < len; q += 8) {
            const float w0 = lal[q] * inv;
            const int   n0 = lnode[q];
            const float w1 = lal[q + 4] * inv;
            const int   n1 = lnode[q + 4];
            const unsigned int v0 =
                *reinterpret_cast<const unsigned int*>(mb + (size_t)n0 * RHD + (jj << 1));
            const unsigned int v1 =
                *reinterpret_cast<const unsigned int*>(mb + (size_t)n1 * RHD + (jj << 1));
            a0 = fmaf(w0, bfu(v0 & 0xffffu), a0);
            a1 = fmaf(w0, bfu(v0 >> 16), a1);
            a0 = fmaf(w1, bfu(v1 & 0xffffu), a0);
            a1 = fmaf(w1, bfu(v1 >> 16), a1);
        }
        if (q < len) {
            const float w0 = lal[q] * inv;
            const int   n0 = lnode[q];
            const unsigned int v0 =
                *reinterpret_cast<const unsigned int*>(mb + (size_t)n0 * RHD + (jj << 1));
            a0 = fmaf(w0, bfu(v0 & 0xffffu), a0);
            a1 = fmaf(w0, bfu(v0 >> 16), a1);
        }
    } else {
        // ---- streaming fallback (3 passes) ----
        float m = -INFINITY;
        for (int i = tid; i < len; i += 256) m = fmaxf(m, __int_as_float(rc[i].y));
#pragma unroll
        for (int off = 32; off > 0; off >>= 1) m = fmaxf(m, __shfl_xor(m, off));
        if ((tid & 63) == 0) red[slot] = m;
        __syncthreads();
        m = fmaxf(fmaxf(red[0], red[1]), fmaxf(red[2], red[3]));
        __syncthreads();

        float sum = 0.f;
        for (int i = tid; i < len; i += 256) sum += __expf(__int_as_float(rc[i].y) - m);
#pragma unroll
        for (int off = 32; off > 0; off >>= 1) sum += __shfl_xor(sum, off);
        if ((tid & 63) == 0) red[4 + slot] = sum;
        __syncthreads();
        sum = red[4] + red[5] + red[6] + red[7];
        const float inv = 1.f / sum;

        for (int c0 = 0; c0 < len; c0 += 256) {
            __syncthreads();
            int i = c0 + tid;
            if (i < len) {
                int2 v = rc[i];
                lal[tid] = __expf(__int_as_float(v.y) - m) * inv;
                lnode[tid] = v.x;
            }
            __syncthreads();
            const int nc = min(256, len - c0);
            for (int q = slot; q < nc; q += 4) {
                const float wq = lal[q];
                const int n = lnode[q];
                const unsigned int v =
                    *reinterpret_cast<const unsigned int*>(mb + (size_t)n * RHD + (jj << 1));
                a0 = fmaf(wq, bfu(v & 0xffffu), a0);
                a1 = fmaf(wq, bfu(v >> 16), a1);
            }
        }
    }

    part[slot][(jj << 1) + 0] = a0;
    part[slot][(jj << 1) + 1] = a1;
    __syncthreads();
    if (tid < 128) {
        float v = part[0][tid] + part[1][tid] + part[2][tid] + part[3][tid];
        atomicAdd(&out[(size_t)r * RHD + tid], v);
    }
}

// ---------------------------------------------------------------------------
extern "C" void kernel_launch(void* const* d_in, const int* in_sizes, int n_in,
                              void* d_out, int out_size, void* d_ws, size_t ws_size,
                              hipStream_t stream)
{
    const float* xe  = (const float*)d_in[0];
    const int*  eidx = (const int*)d_in[1];
    const int*  rel  = (const int*)d_in[2];
    const float* wh  = (const float*)d_in[4];
    const float* wt  = (const float*)d_in[5];
    const float* ah1 = (const float*)d_in[6];
    const float* ah2 = (const float*)d_in[7];
    const float* at1 = (const float*)d_in[8];
    const float* at2 = (const float*)d_in[9];
    const float* rhw = (const float*)d_in[10];
    const float* rhb = (const float*)d_in[11];
    const float* rtw = (const float*)d_in[12];
    const float* rtb = (const float*)d_in[13];
    float* out = (float*)d_out;

    const int N = in_sizes[0] / EHD;
    const int E = in_sizes[2];
    const int R = out_size / RHD;
    const int* eh = eidx;
    const int* et = eidx + E;

    char* ws = (char*)d_ws;
    size_t off = 0;
    auto alloc = [&](size_t bytes) -> void* {
        void* p = ws + off;
        off = (off + bytes + 255) & ~(size_t)255;
        return p;
    };
    short* msgh  = (short*)alloc((size_t)N * RHD * sizeof(short));
    short* msgt  = (short*)alloc((size_t)N * RHD * sizeof(short));
    short* whT   = (short*)alloc((size_t)RHD * EHD * sizeof(short));
    short* wtT   = (short*)alloc((size_t)RHD * EHD * sizeof(short));
    short* rhwT  = (short*)alloc((size_t)RHD * RHD * sizeof(short));
    short* rtwT  = (short*)alloc((size_t)RHD * RHD * sizeof(short));
    float* s1    = (float*)alloc((size_t)N * sizeof(float));
    float* s2    = (float*)alloc((size_t)N * sizeof(float));
    float* s3    = (float*)alloc((size_t)N * sizeof(float));
    float* s4    = (float*)alloc((size_t)N * sizeof(float));
    int* counts  = (int*)alloc((size_t)R * sizeof(int));
    int* starts  = (int*)alloc((size_t)(R + 1) * sizeof(int));
    int* cursor  = (int*)alloc((size_t)R * sizeof(int));
    int2* rec1   = (int2*)alloc((size_t)E * sizeof(int2));
    int2* rec2   = (int2*)alloc((size_t)E * sizeof(int2));
    (void)ws_size; (void)n_in;

    hipMemsetAsync(counts, 0, (size_t)R * sizeof(int), stream);
    hipMemsetAsync(out, 0, (size_t)out_size * sizeof(float), stream);

    k_prep<<<dim3(EHD / 32, RHD / 32), 256, 0, stream>>>(wh, whT, EHD, RHD);
    k_prep<<<dim3(EHD / 32, RHD / 32), 256, 0, stream>>>(wt, wtT, EHD, RHD);
    k_prep<<<dim3(RHD / 32, RHD / 32), 256, 0, stream>>>(rhw, rhwT, RHD, RHD);
    k_prep<<<dim3(RHD / 32, RHD / 32), 256, 0, stream>>>(rtw, rtwT, RHD, RHD);

    k_fused<<<(N + 63) / 64, 256, 0, stream>>>(
        xe, whT, wtT, rhwT, rtwT, rhb, rtb, ah1, ah2, at1, at2,
        s1, s2, s3, s4, msgh, msgt, N);

    k_hist<<<128, 256, 0, stream>>>(rel, counts, R, E);
    k_scan<<<1, 1024, 0, stream>>>(counts, starts, cursor, R, E);
    k_scatter<<<(E + SCHUNK - 1) / SCHUNK, 256, 0, stream>>>(
        rel, cursor, eh, et, s1, s2, s3, s4, rec1, rec2, R, E);
    k_rel<<<dim3(R, 2), 256, 0, stream>>>(starts, rec1, rec2, msgh, msgt, out);
}

// Round 5
// 172.013 us; speedup vs baseline: 3.6134x; 1.0664x over previous
//
#include <hip/hip_runtime.h>
#include <hip/hip_bf16.h>
#include <math.h>

// ---------------------------------------------------------------------------
// GAT_E_to_R: N=100000, E=500000, EH=256, RH=128, R=1000
// Dense pipeline fused into one bf16-MFMA kernel (reg-prefetched staging,
// swizzled LDS); edge phase: block-privatized CSR scatter into packed
// records, per-(relation,side) softmax+reduce with LDS-cached segments.
// ---------------------------------------------------------------------------

#define EHD 256
#define RHD 128
#define BSTR 40     // Bs row stride in shorts (80B)
#define RMAX 1024
#define SCHUNK 2048 // edges per scatter block
#define SEGMAX 4096 // max cached segment length in k_rel

typedef __attribute__((ext_vector_type(8))) short short8;
typedef __attribute__((ext_vector_type(4))) float f32x4;

__device__ __forceinline__ short f2bf(float x) {
    __hip_bfloat16 b = __float2bfloat16(x);   // RNE
    return *reinterpret_cast<short*>(&b);
}
__device__ __forceinline__ float bf2f(short s) {
    __hip_bfloat16 b = *reinterpret_cast<__hip_bfloat16*>(&s);
    return __bfloat162float(b);
}
__device__ __forceinline__ float bfu(unsigned int u) {
    return __uint_as_float(u << 16);
}
__device__ __forceinline__ float leaky(float x) { return x > 0.f ? x : 0.01f * x; }
// Xs swizzle: XOR 16B chunk index with row&7 (keeps short8 alignment)
__device__ __forceinline__ int xswz(int row, int col) {
    return col ^ ((row & 7) << 3);
}

// ---- transpose+convert: dst[n][k] (bf16) = src[k][n] (fp32) ----------------
__global__ __launch_bounds__(256) void k_prep(const float* __restrict__ src,
                                              short* __restrict__ dst,
                                              int K, int Nc)
{
    __shared__ float t[32][33];
    const int k0 = blockIdx.x * 32, n0 = blockIdx.y * 32;
    const int tr = threadIdx.x >> 3, tc = (threadIdx.x & 7) << 2;
    float4 v = *reinterpret_cast<const float4*>(src + (size_t)(k0 + tr) * Nc + n0 + tc);
    t[tr][tc + 0] = v.x; t[tr][tc + 1] = v.y;
    t[tr][tc + 2] = v.z; t[tr][tc + 3] = v.w;
    __syncthreads();
    short* o = dst + (size_t)(n0 + tr) * K + k0 + tc;
    o[0] = f2bf(t[tc + 0][tr]); o[1] = f2bf(t[tc + 1][tr]);
    o[2] = f2bf(t[tc + 2][tr]); o[3] = f2bf(t[tc + 3][tr]);
}

// ---- fused: xr = xe@{wh,wt}; s1..s4; msg(bf16) = xr@{rhw,rtw} + b + xr ------
__global__ __launch_bounds__(256, 3) void k_fused(
    const float* __restrict__ xe,
    const short* __restrict__ whT, const short* __restrict__ wtT,   // [128][256]
    const short* __restrict__ rhwT, const short* __restrict__ rtwT, // [128][128]
    const float* __restrict__ rhb, const float* __restrict__ rtb,
    const float* __restrict__ ah1, const float* __restrict__ ah2,
    const float* __restrict__ at1, const float* __restrict__ at2,
    float* __restrict__ s1, float* __restrict__ s2,
    float* __restrict__ s3, float* __restrict__ s4,
    short* __restrict__ msgh, short* __restrict__ msgt, int N)
{
    __shared__ __align__(16) short Bs[2][128][BSTR];   // 20480 B
    __shared__ __align__(16) short Xs[2][64][128];     // 32768 B (swizzled)

    const int tid = threadIdx.x;
    const int w = tid >> 6, l = tid & 63;
    const int ln = l & 15, lk = l >> 4;
    const int m0 = blockIdx.x * 64;
    const int sn = tid >> 1, sh = (tid & 1) << 4;
    const int orow = (w << 4) + (lk << 2);

    f32x4 acch[8], acct[8];
#pragma unroll
    for (int c = 0; c < 8; c++) {
        acch[c] = (f32x4){0.f, 0.f, 0.f, 0.f};
        acct[c] = (f32x4){0.f, 0.f, 0.f, 0.f};
    }

    // -------- GEMM1: K=256, 8 k-steps, reg-prefetched staging --------
    const int arow = m0 + (w << 4) + ln;
    const int aclamp = min(arow, N - 1);
    const float* abase = xe + (size_t)aclamp * EHD + (lk << 3);
    const short* pB0 = whT + (size_t)sn * EHD + sh;
    const short* pB1 = wtT + (size_t)sn * EHD + sh;

    short8 b0 = *reinterpret_cast<const short8*>(pB0);
    short8 b1 = *reinterpret_cast<const short8*>(pB0 + 8);
    short8 b2 = *reinterpret_cast<const short8*>(pB1);
    short8 b3 = *reinterpret_cast<const short8*>(pB1 + 8);
    float4 a0 = *reinterpret_cast<const float4*>(abase);
    float4 a1 = *reinterpret_cast<const float4*>(abase + 4);

#pragma unroll
    for (int s = 0; s < 8; s++) {
        const int kt = s << 5;
        __syncthreads();           // Bs free (previous reads done)
        *reinterpret_cast<short8*>(&Bs[0][sn][sh + 0]) = b0;
        *reinterpret_cast<short8*>(&Bs[0][sn][sh + 8]) = b1;
        *reinterpret_cast<short8*>(&Bs[1][sn][sh + 0]) = b2;
        *reinterpret_cast<short8*>(&Bs[1][sn][sh + 8]) = b3;
        short8 af;
        af[0] = f2bf(a0.x); af[1] = f2bf(a0.y); af[2] = f2bf(a0.z); af[3] = f2bf(a0.w);
        af[4] = f2bf(a1.x); af[5] = f2bf(a1.y); af[6] = f2bf(a1.z); af[7] = f2bf(a1.w);
        if (s < 7) {               // issue next-step loads; in flight over MFMA+barrier
            b0 = *reinterpret_cast<const short8*>(pB0 + kt + 32);
            b1 = *reinterpret_cast<const short8*>(pB0 + kt + 40);
            b2 = *reinterpret_cast<const short8*>(pB1 + kt + 32);
            b3 = *reinterpret_cast<const short8*>(pB1 + kt + 40);
            a0 = *reinterpret_cast<const float4*>(abase + kt + 32);
            a1 = *reinterpret_cast<const float4*>(abase + kt + 36);
        }
        __syncthreads();           // Bs ready
#pragma unroll
        for (int c = 0; c < 8; c++) {
            short8 bh = *reinterpret_cast<const short8*>(&Bs[0][(c << 4) + ln][lk << 3]);
            short8 bt = *reinterpret_cast<const short8*>(&Bs[1][(c << 4) + ln][lk << 3]);
            acch[c] = __builtin_amdgcn_mfma_f32_16x16x32_bf16(af, bh, acch[c], 0, 0, 0);
            acct[c] = __builtin_amdgcn_mfma_f32_16x16x32_bf16(af, bt, acct[c], 0, 0, 0);
        }
    }

    // issue GEMM2's first B-stage now; latency hides under epilogue 1
    const short* qB0 = rhwT + (size_t)sn * RHD + sh;
    const short* qB1 = rtwT + (size_t)sn * RHD + sh;
    b0 = *reinterpret_cast<const short8*>(qB0);
    b1 = *reinterpret_cast<const short8*>(qB0 + 8);
    b2 = *reinterpret_cast<const short8*>(qB1);
    b3 = *reinterpret_cast<const short8*>(qB1 + 8);

    // -------- epilogue 1: scalars from fp32 acc; xr -> LDS bf16 (swizzled) ---
    float p1[4] = {0,0,0,0}, p2[4] = {0,0,0,0}, p3[4] = {0,0,0,0}, p4[4] = {0,0,0,0};
#pragma unroll
    for (int c = 0; c < 8; c++) {
        const int col = (c << 4) + ln;
        const float wa1 = ah1[col], wa2 = ah2[col], wa3 = at1[col], wa4 = at2[col];
#pragma unroll
        for (int r = 0; r < 4; r++) {
            const float vh = acch[c][r], vt = acct[c][r];
            p1[r] = fmaf(vh, wa1, p1[r]);
            p3[r] = fmaf(vh, wa3, p3[r]);
            p2[r] = fmaf(vt, wa2, p2[r]);
            p4[r] = fmaf(vt, wa4, p4[r]);
            const int row = orow + r;
            const int cs = xswz(row, col);
            Xs[0][row][cs] = f2bf(vh);
            Xs[1][row][cs] = f2bf(vt);
        }
    }
#pragma unroll
    for (int off = 1; off < 16; off <<= 1) {
#pragma unroll
        for (int r = 0; r < 4; r++) {
            p1[r] += __shfl_xor(p1[r], off);
            p2[r] += __shfl_xor(p2[r], off);
            p3[r] += __shfl_xor(p3[r], off);
            p4[r] += __shfl_xor(p4[r], off);
        }
    }
    if (ln == 0) {
#pragma unroll
        for (int r = 0; r < 4; r++) {
            const int grow = m0 + orow + r;
            if (grow < N) {
                s1[grow] = p1[r]; s2[grow] = p2[r];
                s3[grow] = p3[r]; s4[grow] = p4[r];
            }
        }
    }

    // -------- GEMM2: msg = xr @ {rhw,rtw}, K=128, 4 k-steps ------------------
    f32x4 a2h[8], a2t[8];
#pragma unroll
    for (int c = 0; c < 8; c++) {
        a2h[c] = (f32x4){0.f, 0.f, 0.f, 0.f};
        a2t[c] = (f32x4){0.f, 0.f, 0.f, 0.f};
    }
    const int xrow = (w << 4) + ln;
#pragma unroll
    for (int s = 0; s < 4; s++) {
        const int kt = s << 5;
        __syncthreads();    // covers epi1 Xs writes (s=0) / prev Bs reads
        *reinterpret_cast<short8*>(&Bs[0][sn][sh + 0]) = b0;
        *reinterpret_cast<short8*>(&Bs[0][sn][sh + 8]) = b1;
        *reinterpret_cast<short8*>(&Bs[1][sn][sh + 0]) = b2;
        *reinterpret_cast<short8*>(&Bs[1][sn][sh + 8]) = b3;
        if (s < 3) {
            b0 = *reinterpret_cast<const short8*>(qB0 + kt + 32);
            b1 = *reinterpret_cast<const short8*>(qB0 + kt + 40);
            b2 = *reinterpret_cast<const short8*>(qB1 + kt + 32);
            b3 = *reinterpret_cast<const short8*>(qB1 + kt + 40);
        }
        __syncthreads();
        const int xc = (kt + (lk << 3)) ^ ((xrow & 7) << 3);
        short8 ahf = *reinterpret_cast<const short8*>(&Xs[0][xrow][xc]);
        short8 avf = *reinterpret_cast<const short8*>(&Xs[1][xrow][xc]);
#pragma unroll
        for (int c = 0; c < 8; c++) {
            short8 bh = *reinterpret_cast<const short8*>(&Bs[0][(c << 4) + ln][lk << 3]);
            short8 bt = *reinterpret_cast<const short8*>(&Bs[1][(c << 4) + ln][lk << 3]);
            a2h[c] = __builtin_amdgcn_mfma_f32_16x16x32_bf16(ahf, bh, a2h[c], 0, 0, 0);
            a2t[c] = __builtin_amdgcn_mfma_f32_16x16x32_bf16(avf, bt, a2t[c], 0, 0, 0);
        }
    }

    // -------- epilogue 2: msg = acc + bias + residual -> bf16 via Xs ---------
#pragma unroll
    for (int c = 0; c < 8; c++) {
        const int col = (c << 4) + ln;
        const float bh = rhb[col], bt = rtb[col];
#pragma unroll
        for (int r = 0; r < 4; r++) {
            const int row = orow + r;
            const int cs = xswz(row, col);
            a2h[c][r] += bh + bf2f(Xs[0][row][cs]);
            a2t[c][r] += bt + bf2f(Xs[1][row][cs]);
        }
    }
    __syncthreads();   // all GEMM2 A-reads + residual reads done
#pragma unroll
    for (int c = 0; c < 8; c++) {
        const int col = (c << 4) + ln;
#pragma unroll
        for (int r = 0; r < 4; r++) {
            const int row = orow + r;
            const int cs = xswz(row, col);
            Xs[0][row][cs] = f2bf(a2h[c][r]);
            Xs[1][row][cs] = f2bf(a2t[c][r]);
        }
    }
    __syncthreads();
#pragma unroll
    for (int it = 0; it < 8; it++) {
        const int idx = tid + (it << 8);
        const int mat = idx >> 10;
        const int rem = idx & 1023;
        const int row = rem >> 4;
        const int ch  = rem & 15;
        const int grow = m0 + row;
        if (grow < N) {
            const int cs = (ch << 3) ^ ((row & 7) << 3);
            short8 v = *reinterpret_cast<const short8*>(&Xs[mat][row][cs]);
            short* dst = (mat ? msgt : msgh) + (size_t)grow * RHD + (ch << 3);
            *reinterpret_cast<short8*>(dst) = v;
        }
    }
}

// ---------------- CSR sort by relation --------------------------------------
__global__ __launch_bounds__(256) void k_hist(const int* __restrict__ rel,
                                              int* __restrict__ counts, int R, int E)
{
    __shared__ int cnt[RMAX];
    for (int i = threadIdx.x; i < R; i += 256) cnt[i] = 0;
    __syncthreads();
    for (int e = blockIdx.x * 256 + threadIdx.x; e < E; e += gridDim.x * 256)
        atomicAdd(&cnt[rel[e]], 1);
    __syncthreads();
    for (int i = threadIdx.x; i < R; i += 256) {
        int v = cnt[i];
        if (v) atomicAdd(&counts[i], v);
    }
}

__global__ __launch_bounds__(1024) void k_scan(
    const int* __restrict__ counts, int* __restrict__ starts,
    int* __restrict__ cursor, int R, int E)
{
    __shared__ int buf[2][1024];
    int t = threadIdx.x;
    int v = (t < R) ? counts[t] : 0;
    buf[0][t] = v;
    int cur = 0;
    for (int off = 1; off < 1024; off <<= 1) {
        __syncthreads();
        int x = buf[cur][t];
        if (t >= off) x += buf[cur][t - off];
        buf[cur ^ 1][t] = x;
        cur ^= 1;
    }
    __syncthreads();
    int incl = buf[cur][t];
    if (t < R) { starts[t] = incl - v; cursor[t] = incl - v; }
    if (t == 0) starts[R] = E;
}

// ---- block-privatized scatter into packed records ---------------------------
__global__ __launch_bounds__(256) void k_scatter(
    const int* __restrict__ rel, int* __restrict__ cursor,
    const int* __restrict__ eh, const int* __restrict__ et,
    const float* __restrict__ s1, const float* __restrict__ s2,
    const float* __restrict__ s3, const float* __restrict__ s4,
    int2* __restrict__ rec1, int2* __restrict__ rec2, int R, int E)
{
    __shared__ int lcnt[RMAX];
    __shared__ int lbase[RMAX];
    const int tid = threadIdx.x;
    const int base = blockIdx.x * SCHUNK;
    const int nE = min(SCHUNK, E - base);
    for (int i = tid; i < R; i += 256) lcnt[i] = 0;
    __syncthreads();
    for (int i = tid; i < nE; i += 256) atomicAdd(&lcnt[rel[base + i]], 1);
    __syncthreads();
    for (int r = tid; r < R; r += 256) {
        int c = lcnt[r];
        lbase[r] = c ? atomicAdd(&cursor[r], c) : 0;
        lcnt[r] = 0;
    }
    __syncthreads();
    for (int i = tid; i < nE; i += 256) {
        const int e = base + i;
        const int r = rel[e];
        const int off = atomicAdd(&lcnt[r], 1);
        const int pos = lbase[r] + off;
        const int h = eh[e], t = et[e];
        const float e1 = leaky(s1[h] + s2[t]);
        const float e2 = leaky(s3[h] + s4[t]);
        rec1[pos] = make_int2(h, __float_as_int(e1));
        rec2[pos] = make_int2(t, __float_as_int(e2));
    }
}

// ---------------- per-(relation,side) softmax + weighted reduce -------------
__global__ __launch_bounds__(256) void k_rel(
    const int* __restrict__ starts,
    const int2* __restrict__ rec1, const int2* __restrict__ rec2,
    const short* __restrict__ msgh, const short* __restrict__ msgt,
    float* __restrict__ out)
{
    const int r = blockIdx.x;
    const int side = blockIdx.y;
    const int start = starts[r], end = starts[r + 1];
    const int len = end - start;
    if (len <= 0) return;                        // out pre-zeroed
    const int tid = threadIdx.x;
    const int2* __restrict__ rc = (side ? rec2 : rec1) + start;
    const unsigned short* __restrict__ mb =
        reinterpret_cast<const unsigned short*>(side ? msgt : msgh);

    __shared__ float red[8];
    __shared__ int   lnode[SEGMAX];
    __shared__ float lal[SEGMAX];
    __shared__ float part[4][128];

    const int slot = tid >> 6;        // wave id
    const int jj = tid & 63;          // column pair
    float a0 = 0.f, a1 = 0.f;

    if (len <= SEGMAX) {
        float m = -INFINITY;
        for (int i = tid; i < len; i += 256) {
            int2 v = rc[i];
            lnode[i] = v.x;
            float e = __int_as_float(v.y);
            lal[i] = e;
            m = fmaxf(m, e);
        }
#pragma unroll
        for (int off = 32; off > 0; off >>= 1) m = fmaxf(m, __shfl_xor(m, off));
        if ((tid & 63) == 0) red[slot] = m;
        __syncthreads();
        m = fmaxf(fmaxf(red[0], red[1]), fmaxf(red[2], red[3]));
        __syncthreads();

        float sum = 0.f;
        for (int i = tid; i < len; i += 256) {
            float x = __expf(lal[i] - m);
            lal[i] = x;
            sum += x;
        }
#pragma unroll
        for (int off = 32; off > 0; off >>= 1) sum += __shfl_xor(sum, off);
        if ((tid & 63) == 0) red[4 + slot] = sum;
        __syncthreads();
        sum = red[4] + red[5] + red[6] + red[7];
        const float inv = 1.f / sum;

        int q = slot;
        for (; q + 4 < len; q += 8) {
            const float w0 = lal[q] * inv;
            const int   n0 = lnode[q];
            const float w1 = lal[q + 4] * inv;
            const int   n1 = lnode[q + 4];
            const unsigned int v0 =
                *reinterpret_cast<const unsigned int*>(mb + (size_t)n0 * RHD + (jj << 1));
            const unsigned int v1 =
                *reinterpret_cast<const unsigned int*>(mb + (size_t)n1 * RHD + (jj << 1));
            a0 = fmaf(w0, bfu(v0 & 0xffffu), a0);
            a1 = fmaf(w0, bfu(v0 >> 16), a1);
            a0 = fmaf(w1, bfu(v1 & 0xffffu), a0);
            a1 = fmaf(w1, bfu(v1 >> 16), a1);
        }
        if (q < len) {
            const float w0 = lal[q] * inv;
            const int   n0 = lnode[q];
            const unsigned int v0 =
                *reinterpret_cast<const unsigned int*>(mb + (size_t)n0 * RHD + (jj << 1));
            a0 = fmaf(w0, bfu(v0 & 0xffffu), a0);
            a1 = fmaf(w0, bfu(v0 >> 16), a1);
        }
    } else {
        float m = -INFINITY;
        for (int i = tid; i < len; i += 256) m = fmaxf(m, __int_as_float(rc[i].y));
#pragma unroll
        for (int off = 32; off > 0; off >>= 1) m = fmaxf(m, __shfl_xor(m, off));
        if ((tid & 63) == 0) red[slot] = m;
        __syncthreads();
        m = fmaxf(fmaxf(red[0], red[1]), fmaxf(red[2], red[3]));
        __syncthreads();

        float sum = 0.f;
        for (int i = tid; i < len; i += 256) sum += __expf(__int_as_float(rc[i].y) - m);
#pragma unroll
        for (int off = 32; off > 0; off >>= 1) sum += __shfl_xor(sum, off);
        if ((tid & 63) == 0) red[4 + slot] = sum;
        __syncthreads();
        sum = red[4] + red[5] + red[6] + red[7];
        const float inv = 1.f / sum;

        for (int c0 = 0; c0 < len; c0 += 256) {
            __syncthreads();
            int i = c0 + tid;
            if (i < len) {
                int2 v = rc[i];
                lal[tid] = __expf(__int_as_float(v.y) - m) * inv;
                lnode[tid] = v.x;
            }
            __syncthreads();
            const int nc = min(256, len - c0);
            for (int q = slot; q < nc; q += 4) {
                const float wq = lal[q];
                const int n = lnode[q];
                const unsigned int v =
                    *reinterpret_cast<const unsigned int*>(mb + (size_t)n * RHD + (jj << 1));
                a0 = fmaf(wq, bfu(v & 0xffffu), a0);
                a1 = fmaf(wq, bfu(v >> 16), a1);
            }
        }
    }

    part[slot][(jj << 1) + 0] = a0;
    part[slot][(jj << 1) + 1] = a1;
    __syncthreads();
    if (tid < 128) {
        float v = part[0][tid] + part[1][tid] + part[2][tid] + part[3][tid];
        atomicAdd(&out[(size_t)r * RHD + tid], v);
    }
}

// ---------------------------------------------------------------------------
extern "C" void kernel_launch(void* const* d_in, const int* in_sizes, int n_in,
                              void* d_out, int out_size, void* d_ws, size_t ws_size,
                              hipStream_t stream)
{
    const float* xe  = (const float*)d_in[0];
    const int*  eidx = (const int*)d_in[1];
    const int*  rel  = (const int*)d_in[2];
    const float* wh  = (const float*)d_in[4];
    const float* wt  = (const float*)d_in[5];
    const float* ah1 = (const float*)d_in[6];
    const float* ah2 = (const float*)d_in[7];
    const float* at1 = (const float*)d_in[8];
    const float* at2 = (const float*)d_in[9];
    const float* rhw = (const float*)d_in[10];
    const float* rhb = (const float*)d_in[11];
    const float* rtw = (const float*)d_in[12];
    const float* rtb = (const float*)d_in[13];
    float* out = (float*)d_out;

    const int N = in_sizes[0] / EHD;
    const int E = in_sizes[2];
    const int R = out_size / RHD;
    const int* eh = eidx;
    const int* et = eidx + E;

    char* ws = (char*)d_ws;
    size_t off = 0;
    auto alloc = [&](size_t bytes) -> void* {
        void* p = ws + off;
        off = (off + bytes + 255) & ~(size_t)255;
        return p;
    };
    short* msgh  = (short*)alloc((size_t)N * RHD * sizeof(short));
    short* msgt  = (short*)alloc((size_t)N * RHD * sizeof(short));
    short* whT   = (short*)alloc((size_t)RHD * EHD * sizeof(short));
    short* wtT   = (short*)alloc((size_t)RHD * EHD * sizeof(short));
    short* rhwT  = (short*)alloc((size_t)RHD * RHD * sizeof(short));
    short* rtwT  = (short*)alloc((size_t)RHD * RHD * sizeof(short));
    float* s1    = (float*)alloc((size_t)N * sizeof(float));
    float* s2    = (float*)alloc((size_t)N * sizeof(float));
    float* s3    = (float*)alloc((size_t)N * sizeof(float));
    float* s4    = (float*)alloc((size_t)N * sizeof(float));
    int* counts  = (int*)alloc((size_t)R * sizeof(int));
    int* starts  = (int*)alloc((size_t)(R + 1) * sizeof(int));
    int* cursor  = (int*)alloc((size_t)R * sizeof(int));
    int2* rec1   = (int2*)alloc((size_t)E * sizeof(int2));
    int2* rec2   = (int2*)alloc((size_t)E * sizeof(int2));
    (void)ws_size; (void)n_in;

    hipMemsetAsync(counts, 0, (size_t)R * sizeof(int), stream);
    hipMemsetAsync(out, 0, (size_t)out_size * sizeof(float), stream);

    k_prep<<<dim3(EHD / 32, RHD / 32), 256, 0, stream>>>(wh, whT, EHD, RHD);
    k_prep<<<dim3(EHD / 32, RHD / 32), 256, 0, stream>>>(wt, wtT, EHD, RHD);
    k_prep<<<dim3(RHD / 32, RHD / 32), 256, 0, stream>>>(rhw, rhwT, RHD, RHD);
    k_prep<<<dim3(RHD / 32, RHD / 32), 256, 0, stream>>>(rtw, rtwT, RHD, RHD);

    k_fused<<<(N + 63) / 64, 256, 0, stream>>>(
        xe, whT, wtT, rhwT, rtwT, rhb, rtb, ah1, ah2, at1, at2,
        s1, s2, s3, s4, msgh, msgt, N);

    k_hist<<<128, 256, 0, stream>>>(rel, counts, R, E);
    k_scan<<<1, 1024, 0, stream>>>(counts, starts, cursor, R, E);
    k_scatter<<<(E + SCHUNK - 1) / SCHUNK, 256, 0, stream>>>(
        rel, cursor, eh, et, s1, s2, s3, s4, rec1, rec2, R, E);
    k_rel<<<dim3(R, 2), 256, 0, stream>>>(starts, rec1, rec2, msgh, msgt, out);
}